// Round 11
// baseline (4739.663 us; speedup 1.0000x reference)
//
#include <hip/hip_runtime.h>
#include <stdint.h>
#include <math.h>

#define NVARS 1024
#define KDIM 32
#define BATCH 64
#define NIN 768
#define MAXIT 10

// LDS layout (bytes):
//   Vs    @ 0       float [1024][32]   131072   (V state, whole kernel)
//   Cd    @ 131072  float [64][64]      16384   (span diagonal block of C)
//   dVs   @ 147456  float [64][32]       8192   (span dv buffer)
//   fmask @ 155648  uint  [32]            128   (free bits, 2 words/span)
//   v0D   @ 155776  double[32]            256
#define SMEM_BYTES 156032

// ---- threefry2x32 block, exactly matching JAX (20 rounds, inject every 4) ----
__device__ __forceinline__ void tf2x32(uint32_t key0, uint32_t key1,
                                       uint32_t& x0, uint32_t& x1) {
  uint32_t ks2 = key0 ^ key1 ^ 0x1BD11BDAu;
  x0 += key0; x1 += key1;
#define TFR(r) { x0 += x1; x1 = (x1 << r) | (x1 >> (32 - r)); x1 ^= x0; }
  TFR(13) TFR(15) TFR(26) TFR(6)
  x0 += key1; x1 += ks2 + 1u;
  TFR(17) TFR(29) TFR(16) TFR(24)
  x0 += ks2;  x1 += key0 + 2u;
  TFR(13) TFR(15) TFR(26) TFR(6)
  x0 += key0; x1 += key1 + 3u;
  TFR(17) TFR(29) TFR(16) TFR(24)
  x0 += key1; x1 += ks2 + 4u;
  TFR(13) TFR(15) TFR(26) TFR(6)
  x0 += ks2;  x1 += key0 + 5u;
#undef TFR
}

// partitionable random_bits (32-bit): counter (0, flat), out = x0 ^ x1
__device__ __forceinline__ uint32_t pbits(uint32_t k0, uint32_t k1, uint32_t flat) {
  uint32_t x0 = 0u, x1 = flat;
  tf2x32(k0, k1, x0, x1);
  return x0 ^ x1;
}

// ---- XLA f32 erf_inv (Giles polynomial) ----
__device__ __forceinline__ float erfinv_xla(float x) {
  float w = -log1pf(-x * x);
  float p;
  if (w < 5.0f) {
    w -= 2.5f;
    p = 2.81022636e-08f;
    p = fmaf(p, w, 3.43273939e-07f);
    p = fmaf(p, w, -3.5233877e-06f);
    p = fmaf(p, w, -4.39150654e-06f);
    p = fmaf(p, w, 0.00021858087f);
    p = fmaf(p, w, -0.00125372503f);
    p = fmaf(p, w, -0.00417768164f);
    p = fmaf(p, w, 0.246640727f);
    p = fmaf(p, w, 1.50140941f);
  } else {
    w = sqrtf(w) - 3.0f;
    p = -0.000200214257f;
    p = fmaf(p, w, 0.000100950558f);
    p = fmaf(p, w, 0.00134934322f);
    p = fmaf(p, w, -0.00367342844f);
    p = fmaf(p, w, 0.00573950773f);
    p = fmaf(p, w, -0.0076224613f);
    p = fmaf(p, w, 0.00943887047f);
    p = fmaf(p, w, 1.00167406f);
    p = fmaf(p, w, 2.83297682f);
  }
  return p * x;
}

__device__ __forceinline__ float bits_to_normal(uint32_t bits) {
  uint32_t fb = (bits >> 9) | 0x3F800000u;
  float f = __uint_as_float(fb) - 1.0f;
  const float lo = -0.99999994f;
  float u = fmaf(f, 2.0f, lo);
  u = fmaxf(lo, u);
  return 1.41421356237f * erfinv_xla(u);
}

__device__ __forceinline__ double red32d(double v) {
  v += __shfl_xor(v, 16);
  v += __shfl_xor(v, 8);
  v += __shfl_xor(v, 4);
  v += __shfl_xor(v, 2);
  v += __shfl_xor(v, 1);
  return v;
}

__device__ __forceinline__ int pop64(uint64_t& b) {
  if (b == 0ull) return -1;
  int i = (int)__builtin_ctzll(b);
  b &= b - 1ull;
  return i;
}

__global__ __launch_bounds__(1024, 4) void mixnet_kernel(
    const float* __restrict__ C32, const float* __restrict__ zin,
    const int* __restrict__ is_in, float* __restrict__ out) {
  extern __shared__ char smemraw[];
  float*    Vs    = (float*)smemraw;                 // [1024][32]
  float*    Cd    = (float*)(smemraw + 131072);      // [64][64]
  float*    dVs   = (float*)(smemraw + 147456);      // [64][32]
  uint32_t* fmask = (uint32_t*)(smemraw + 155648);   // [32]
  double*   v0D   = (double*)(smemraw + 155776);     // [32]

  const int tid  = threadIdx.x;
  const int b    = blockIdx.x;
  const int jg   = tid >> 3;    // 0..127: owns G rows 8jg..8jg+7
  const int kg   = tid & 7;     // 0..7 : owns k 4kg..4kg+3
  const int lane = tid & 63;
  const int wave = tid >> 6;    // 0..15 = span owner index
  const int jgR  = jg & 7;      // row-group within own span

  // ---- free bits (wave w ballots rows 64w..64w+64) ----
  uint32_t myLo, myHi;
  {
    int row = tid;
    bool fr;
    if (row == 0) fr = false;
    else if (row <= NIN) fr = (is_in[b * NIN + row - 1] == 0);
    else fr = true;
    unsigned long long m = __ballot(fr);
    myLo = (uint32_t)m; myHi = (uint32_t)(m >> 32);
    if (lane == 0) { fmask[2 * wave] = myLo; fmask[2 * wave + 1] = myHi; }
  }

  // k1, k2 = jax.random.split(jax.random.key(42))  [partitionable]
  uint32_t a0 = 0u, a1 = 0u; tf2x32(0u, 42u, a0, a1);
  uint32_t b0 = 0u, b1 = 1u; tf2x32(0u, 42u, b0, b1);

  // ---- v0: threads 0..31 (butterfly, bitwise same as R10) ----
  if (tid < 32) {
    float raw = bits_to_normal(pbits(a0, a1, (uint32_t)(b * KDIM + tid)));
    double n2 = red32d((double)raw * (double)raw);
    v0D[tid] = (double)raw / sqrt(n2);
  }
  __syncthreads();

  const double PI_D = 3.14159265358979323846;

  // ---- build V row j = tid (f64 in-thread, bitwise same as R10) ----
  {
    double vrow[32];
    if (tid == 0) {
#pragma unroll
      for (int t = 0; t < 16; ++t) {
        double2 w = *(const double2*)(v0D + 2 * t);
        vrow[2 * t] = w.x; vrow[2 * t + 1] = w.y;
      }
    } else {
      uint32_t base = ((uint32_t)(b * NVARS + tid)) * KDIM;
#pragma unroll
      for (int q = 0; q < 32; ++q)
        vrow[q] = (double)bits_to_normal(pbits(b0, b1, base + (uint32_t)q));
      double dot = 0.0;
#pragma unroll
      for (int t = 0; t < 16; ++t) {
        double2 w = *(const double2*)(v0D + 2 * t);
        dot += vrow[2 * t] * w.x + vrow[2 * t + 1] * w.y;
      }
#pragma unroll
      for (int t = 0; t < 16; ++t) {
        double2 w = *(const double2*)(v0D + 2 * t);
        vrow[2 * t]     -= dot * w.x;
        vrow[2 * t + 1] -= dot * w.y;
      }
      double n2 = 0.0;
#pragma unroll
      for (int q = 0; q < 32; ++q) n2 += vrow[q] * vrow[q];
      double rinv = 1.0 / sqrt(n2);
#pragma unroll
      for (int q = 0; q < 32; ++q) vrow[q] *= rinv;
      if (tid <= NIN && is_in[b * NIN + tid - 1] > 0) {
        double zf = (double)zin[b * NIN + tid - 1];
        double cc = cos(PI_D * zf), sn = sin(PI_D * zf);
#pragma unroll
        for (int t = 0; t < 16; ++t) {
          double2 w = *(const double2*)(v0D + 2 * t);
          vrow[2 * t]     = -cc * w.x + sn * vrow[2 * t];
          vrow[2 * t + 1] = -cc * w.y + sn * vrow[2 * t + 1];
        }
      }
    }
#pragma unroll
    for (int q = 0; q < 8; ++q) {
      float4 w;
      w.x = (float)vrow[4 * q];     w.y = (float)vrow[4 * q + 1];
      w.z = (float)vrow[4 * q + 2]; w.w = (float)vrow[4 * q + 3];
      *(float4*)(Vs + tid * 32 + 4 * q) = w;
    }
  }
  __syncthreads();

  // ---- init G: Gj[l*4+m] = G[8jg+l][4kg+m] (f32, ascending i; as R10) ----
  float Gj[32];
#pragma unroll
  for (int q = 0; q < 32; ++q) Gj[q] = 0.f;
  {
    const float* Cb = C32 + (size_t)(8 * jg) * NVARS;
    for (int i = 0; i < NVARS; i += 4) {
      float4 cw[8];
#pragma unroll
      for (int l = 0; l < 8; ++l)
        cw[l] = *(const float4*)(Cb + (size_t)l * NVARS + i);
#pragma unroll
      for (int u = 0; u < 4; ++u) {
        float4 vv = *(const float4*)(Vs + (i + u) * 32 + 4 * kg);
#pragma unroll
        for (int l = 0; l < 8; ++l) {
          float cu = (u == 0) ? cw[l].x : (u == 1) ? cw[l].y
                   : (u == 2) ? cw[l].z : cw[l].w;
          Gj[l * 4 + 0] = fmaf(cu, vv.x, Gj[l * 4 + 0]);
          Gj[l * 4 + 1] = fmaf(cu, vv.y, Gj[l * 4 + 1]);
          Gj[l * 4 + 2] = fmaf(cu, vv.z, Gj[l * 4 + 2]);
          Gj[l * 4 + 3] = fmaf(cu, vv.w, Gj[l * 4 + 3]);
        }
      }
    }
  }
  __syncthreads();

  // ---- solve: 10 sweeps, span-batched maintained-G Gauss-Seidel ----
  int gPrev = -1;
  for (int it = 0; it < MAXIT; ++it) {
    for (int g = 0; g < 16; ++g) {
      // phase 1: stage Cdiag(g); batch-apply dVs(gPrev) (all waves != gPrev)
      {
        int r = tid >> 4, c4 = (tid & 15) << 2;
        float4 cc = *(const float4*)(C32 + (size_t)(64 * g + r) * NVARS
                                     + 64 * g + c4);
        *(float4*)(Cd + r * 64 + c4) = cc;
      }
      if (gPrev >= 0 && wave != gPrev) {
        uint32_t bl = (uint32_t)__builtin_amdgcn_readfirstlane((int)fmask[2 * gPrev]);
        uint32_t bh = (uint32_t)__builtin_amdgcn_readfirstlane((int)fmask[2 * gPrev + 1]);
        uint64_t bits = ((uint64_t)bh << 32) | (uint64_t)bl;
        const float* Cp = C32 + (size_t)(64 * gPrev) * NVARS + 8 * jg;
        const float* Dp = dVs + 4 * kg;
        int iA = pop64(bits);
        float4 cA0, cA1, dA, cB0, cB1, dB;
        if (iA >= 0) {
          cA0 = *(const float4*)(Cp + (size_t)iA * NVARS);
          cA1 = *(const float4*)(Cp + (size_t)iA * NVARS + 4);
          dA  = *(const float4*)(Dp + iA * 32);
        }
        int iB = pop64(bits);
        if (iB >= 0) {
          cB0 = *(const float4*)(Cp + (size_t)iB * NVARS);
          cB1 = *(const float4*)(Cp + (size_t)iB * NVARS + 4);
          dB  = *(const float4*)(Dp + iB * 32);
        }
        while (iA >= 0) {
          Gj[0]  = fmaf(cA0.x, dA.x, Gj[0]);  Gj[1]  = fmaf(cA0.x, dA.y, Gj[1]);
          Gj[2]  = fmaf(cA0.x, dA.z, Gj[2]);  Gj[3]  = fmaf(cA0.x, dA.w, Gj[3]);
          Gj[4]  = fmaf(cA0.y, dA.x, Gj[4]);  Gj[5]  = fmaf(cA0.y, dA.y, Gj[5]);
          Gj[6]  = fmaf(cA0.y, dA.z, Gj[6]);  Gj[7]  = fmaf(cA0.y, dA.w, Gj[7]);
          Gj[8]  = fmaf(cA0.z, dA.x, Gj[8]);  Gj[9]  = fmaf(cA0.z, dA.y, Gj[9]);
          Gj[10] = fmaf(cA0.z, dA.z, Gj[10]); Gj[11] = fmaf(cA0.z, dA.w, Gj[11]);
          Gj[12] = fmaf(cA0.w, dA.x, Gj[12]); Gj[13] = fmaf(cA0.w, dA.y, Gj[13]);
          Gj[14] = fmaf(cA0.w, dA.z, Gj[14]); Gj[15] = fmaf(cA0.w, dA.w, Gj[15]);
          Gj[16] = fmaf(cA1.x, dA.x, Gj[16]); Gj[17] = fmaf(cA1.x, dA.y, Gj[17]);
          Gj[18] = fmaf(cA1.x, dA.z, Gj[18]); Gj[19] = fmaf(cA1.x, dA.w, Gj[19]);
          Gj[20] = fmaf(cA1.y, dA.x, Gj[20]); Gj[21] = fmaf(cA1.y, dA.y, Gj[21]);
          Gj[22] = fmaf(cA1.y, dA.z, Gj[22]); Gj[23] = fmaf(cA1.y, dA.w, Gj[23]);
          Gj[24] = fmaf(cA1.z, dA.x, Gj[24]); Gj[25] = fmaf(cA1.z, dA.y, Gj[25]);
          Gj[26] = fmaf(cA1.z, dA.z, Gj[26]); Gj[27] = fmaf(cA1.z, dA.w, Gj[27]);
          Gj[28] = fmaf(cA1.w, dA.x, Gj[28]); Gj[29] = fmaf(cA1.w, dA.y, Gj[29]);
          Gj[30] = fmaf(cA1.w, dA.z, Gj[30]); Gj[31] = fmaf(cA1.w, dA.w, Gj[31]);
          iA = iB; cA0 = cB0; cA1 = cB1; dA = dB;
          iB = pop64(bits);
          if (iB >= 0) {
            cB0 = *(const float4*)(Cp + (size_t)iB * NVARS);
            cB1 = *(const float4*)(Cp + (size_t)iB * NVARS + 4);
            dB  = *(const float4*)(Dp + iB * 32);
          }
        }
      }
      __syncthreads();

      // phase 2: serial Gauss-Seidel over span g (wave g only, in-wave sync)
      if (wave == g) {
        const int base = 64 * g;
#pragma unroll
        for (int ii = 0; ii < 64; ++ii) {
          bool on = (ii < 32) ? ((myLo >> ii) & 1u) : ((myHi >> (ii - 32)) & 1u);
          if (!on) continue;                  // wave-uniform skip
          const int m = ii >> 3, l = ii & 7;
          float s = Gj[l * 4 + 0] * Gj[l * 4 + 0];
          s = fmaf(Gj[l * 4 + 1], Gj[l * 4 + 1], s);
          s = fmaf(Gj[l * 4 + 2], Gj[l * 4 + 2], s);
          s = fmaf(Gj[l * 4 + 3], Gj[l * 4 + 3], s);
          s += __shfl_xor(s, 1);
          s += __shfl_xor(s, 2);
          s += __shfl_xor(s, 4);
          float gn  = fmaxf(sqrtf(s), 1e-12f);
          float inv = -1.0f / gn;
          const int row = base + ii;
          float4 vold = *(const float4*)(Vs + row * 32 + 4 * kg);
          float4 vnew, d;
          vnew.x = Gj[l * 4 + 0] * inv; d.x = vnew.x - vold.x;
          vnew.y = Gj[l * 4 + 1] * inv; d.y = vnew.y - vold.y;
          vnew.z = Gj[l * 4 + 2] * inv; d.z = vnew.z - vold.z;
          vnew.w = Gj[l * 4 + 3] * inv; d.w = vnew.w - vold.w;
          if (jgR == m) {
            *(float4*)(Vs + row * 32 + 4 * kg) = vnew;
            *(float4*)(dVs + ii * 32 + 4 * kg) = d;
          }
          d.x = __shfl(d.x, 8 * m + kg);
          d.y = __shfl(d.y, 8 * m + kg);
          d.z = __shfl(d.z, 8 * m + kg);
          d.w = __shfl(d.w, 8 * m + kg);
          float4 c0 = *(const float4*)(Cd + ii * 64 + 8 * jgR);
          float4 c1 = *(const float4*)(Cd + ii * 64 + 8 * jgR + 4);
          Gj[0]  = fmaf(c0.x, d.x, Gj[0]);  Gj[1]  = fmaf(c0.x, d.y, Gj[1]);
          Gj[2]  = fmaf(c0.x, d.z, Gj[2]);  Gj[3]  = fmaf(c0.x, d.w, Gj[3]);
          Gj[4]  = fmaf(c0.y, d.x, Gj[4]);  Gj[5]  = fmaf(c0.y, d.y, Gj[5]);
          Gj[6]  = fmaf(c0.y, d.z, Gj[6]);  Gj[7]  = fmaf(c0.y, d.w, Gj[7]);
          Gj[8]  = fmaf(c0.z, d.x, Gj[8]);  Gj[9]  = fmaf(c0.z, d.y, Gj[9]);
          Gj[10] = fmaf(c0.z, d.z, Gj[10]); Gj[11] = fmaf(c0.z, d.w, Gj[11]);
          Gj[12] = fmaf(c0.w, d.x, Gj[12]); Gj[13] = fmaf(c0.w, d.y, Gj[13]);
          Gj[14] = fmaf(c0.w, d.z, Gj[14]); Gj[15] = fmaf(c0.w, d.w, Gj[15]);
          Gj[16] = fmaf(c1.x, d.x, Gj[16]); Gj[17] = fmaf(c1.x, d.y, Gj[17]);
          Gj[18] = fmaf(c1.x, d.z, Gj[18]); Gj[19] = fmaf(c1.x, d.w, Gj[19]);
          Gj[20] = fmaf(c1.y, d.x, Gj[20]); Gj[21] = fmaf(c1.y, d.y, Gj[21]);
          Gj[22] = fmaf(c1.y, d.z, Gj[22]); Gj[23] = fmaf(c1.y, d.w, Gj[23]);
          Gj[24] = fmaf(c1.z, d.x, Gj[24]); Gj[25] = fmaf(c1.z, d.y, Gj[25]);
          Gj[26] = fmaf(c1.z, d.z, Gj[26]); Gj[27] = fmaf(c1.z, d.w, Gj[27]);
          Gj[28] = fmaf(c1.w, d.x, Gj[28]); Gj[29] = fmaf(c1.w, d.y, Gj[29]);
          Gj[30] = fmaf(c1.w, d.z, Gj[30]); Gj[31] = fmaf(c1.w, d.w, Gj[31]);
        }
      }
      __syncthreads();
      gPrev = g;
    }
  }

  // ---- epilogue: thread=j, V from Vs, f64 ----
  if (tid >= 1 && tid <= NIN) {
    bool fr = (tid < 64) ? (((tid < 32 ? fmask[0] : fmask[1]) >> (tid & 31)) & 1u)
                         : ((fmask[(tid >> 5)] >> (tid & 31)) & 1u);
    float zo;
    if (fr) {
      double dot = 0.0;
#pragma unroll
      for (int t = 0; t < 16; ++t) {
        double2 w = *(const double2*)(v0D + 2 * t);
        dot += (double)Vs[tid * 32 + 2 * t] * w.x
             + (double)Vs[tid * 32 + 2 * t + 1] * w.y;
      }
      double ca = fmin(fmax(-dot, -1.0 + 1e-7), 1.0 - 1e-7);
      zo = (float)(acos(ca) / PI_D);
    } else {
      zo = zin[b * NIN + tid - 1];
    }
    out[b * NIN + tid - 1] = zo;
  }
}

extern "C" void kernel_launch(void* const* d_in, const int* in_sizes, int n_in,
                              void* d_out, int out_size, void* d_ws, size_t ws_size,
                              hipStream_t stream) {
  const float* C        = (const float*)d_in[0];
  const float* z        = (const float*)d_in[1];
  const int*   is_input = (const int*)d_in[2];
  float*       out      = (float*)d_out;
  (void)d_ws; (void)ws_size;

  (void)hipFuncSetAttribute((const void*)mixnet_kernel,
                            hipFuncAttributeMaxDynamicSharedMemorySize,
                            SMEM_BYTES);

  mixnet_kernel<<<BATCH, 1024, SMEM_BYTES, stream>>>(C, z, is_input, out);
}

// Round 12
// 3866.477 us; speedup vs baseline: 1.2258x; 1.2258x over previous
//
#include <hip/hip_runtime.h>
#include <stdint.h>
#include <math.h>

#define NVARS 1024
#define KDIM 32
#define BATCH 64
#define NIN 768
#define MAXIT 10

// LDS layout (bytes):
//   Vs    @ 0       float [1024][32]   131072   (V state)
//   Cd    @ 131072  float [64][64]      16384   (span diagonal block, producer coeffs)
//   dVs   @ 147456  float [64][32]       8192   (span dv ring, indexed by publish order)
//   fmask @ 155648  uint  [32]            128
//   v0D   @ 155776  double[32]            256
//   prog  @ 156032  int   [2]              64   (publish counters, parity-buffered)
#define SMEM_BYTES 156096

// ---- threefry2x32 block, exactly matching JAX (20 rounds, inject every 4) ----
__device__ __forceinline__ void tf2x32(uint32_t key0, uint32_t key1,
                                       uint32_t& x0, uint32_t& x1) {
  uint32_t ks2 = key0 ^ key1 ^ 0x1BD11BDAu;
  x0 += key0; x1 += key1;
#define TFR(r) { x0 += x1; x1 = (x1 << r) | (x1 >> (32 - r)); x1 ^= x0; }
  TFR(13) TFR(15) TFR(26) TFR(6)
  x0 += key1; x1 += ks2 + 1u;
  TFR(17) TFR(29) TFR(16) TFR(24)
  x0 += ks2;  x1 += key0 + 2u;
  TFR(13) TFR(15) TFR(26) TFR(6)
  x0 += key0; x1 += key1 + 3u;
  TFR(17) TFR(29) TFR(16) TFR(24)
  x0 += key1; x1 += ks2 + 4u;
  TFR(13) TFR(15) TFR(26) TFR(6)
  x0 += ks2;  x1 += key0 + 5u;
#undef TFR
}

// partitionable random_bits (32-bit): counter (0, flat), out = x0 ^ x1
__device__ __forceinline__ uint32_t pbits(uint32_t k0, uint32_t k1, uint32_t flat) {
  uint32_t x0 = 0u, x1 = flat;
  tf2x32(k0, k1, x0, x1);
  return x0 ^ x1;
}

// ---- XLA f32 erf_inv (Giles polynomial) ----
__device__ __forceinline__ float erfinv_xla(float x) {
  float w = -log1pf(-x * x);
  float p;
  if (w < 5.0f) {
    w -= 2.5f;
    p = 2.81022636e-08f;
    p = fmaf(p, w, 3.43273939e-07f);
    p = fmaf(p, w, -3.5233877e-06f);
    p = fmaf(p, w, -4.39150654e-06f);
    p = fmaf(p, w, 0.00021858087f);
    p = fmaf(p, w, -0.00125372503f);
    p = fmaf(p, w, -0.00417768164f);
    p = fmaf(p, w, 0.246640727f);
    p = fmaf(p, w, 1.50140941f);
  } else {
    w = sqrtf(w) - 3.0f;
    p = -0.000200214257f;
    p = fmaf(p, w, 0.000100950558f);
    p = fmaf(p, w, 0.00134934322f);
    p = fmaf(p, w, -0.00367342844f);
    p = fmaf(p, w, 0.00573950773f);
    p = fmaf(p, w, -0.0076224613f);
    p = fmaf(p, w, 0.00943887047f);
    p = fmaf(p, w, 1.00167406f);
    p = fmaf(p, w, 2.83297682f);
  }
  return p * x;
}

__device__ __forceinline__ float bits_to_normal(uint32_t bits) {
  uint32_t fb = (bits >> 9) | 0x3F800000u;
  float f = __uint_as_float(fb) - 1.0f;
  const float lo = -0.99999994f;
  float u = fmaf(f, 2.0f, lo);
  u = fmaxf(lo, u);
  return 1.41421356237f * erfinv_xla(u);
}

__device__ __forceinline__ double red32d(double v) {
  v += __shfl_xor(v, 16);
  v += __shfl_xor(v, 8);
  v += __shfl_xor(v, 4);
  v += __shfl_xor(v, 2);
  v += __shfl_xor(v, 1);
  return v;
}

__device__ __forceinline__ int pop64(uint64_t& b) {
  if (b == 0ull) return -1;
  int i = (int)__builtin_ctzll(b);
  b &= b - 1ull;
  return i;
}

__global__ __launch_bounds__(1024, 4) void mixnet_kernel(
    const float* __restrict__ C32, const float* __restrict__ zin,
    const int* __restrict__ is_in, float* __restrict__ out) {
  extern __shared__ char smemraw[];
  float*    Vs    = (float*)smemraw;                 // [1024][32]
  float*    Cd    = (float*)(smemraw + 131072);      // [64][64]
  float*    dVs   = (float*)(smemraw + 147456);      // [64][32]
  uint32_t* fmask = (uint32_t*)(smemraw + 155648);   // [32]
  double*   v0D   = (double*)(smemraw + 155776);     // [32]
  volatile int* progV = (volatile int*)(smemraw + 156032);  // [2]

  const int tid  = threadIdx.x;
  const int b    = blockIdx.x;
  const int jg   = tid >> 3;    // 0..127: owns G rows 8jg..8jg+7
  const int kg   = tid & 7;     // 0..7 : owns k 4kg..4kg+3
  const int lane = tid & 63;
  const int wave = tid >> 6;    // 0..15 = span owner index
  const int jgR  = jg & 7;      // row-group within own span

  // ---- free bits (wave w ballots rows 64w..64w+64) ----
  uint32_t myLo, myHi;
  {
    int row = tid;
    bool fr;
    if (row == 0) fr = false;
    else if (row <= NIN) fr = (is_in[b * NIN + row - 1] == 0);
    else fr = true;
    unsigned long long m = __ballot(fr);
    myLo = (uint32_t)m; myHi = (uint32_t)(m >> 32);
    if (lane == 0) { fmask[2 * wave] = myLo; fmask[2 * wave + 1] = myHi; }
  }
  if (tid == 0) { progV[0] = 0; progV[1] = 0; }

  // k1, k2 = jax.random.split(jax.random.key(42))  [partitionable]
  uint32_t a0 = 0u, a1 = 0u; tf2x32(0u, 42u, a0, a1);
  uint32_t b0 = 0u, b1 = 1u; tf2x32(0u, 42u, b0, b1);

  // ---- v0: threads 0..31 (butterfly, bitwise same as R11) ----
  if (tid < 32) {
    float raw = bits_to_normal(pbits(a0, a1, (uint32_t)(b * KDIM + tid)));
    double n2 = red32d((double)raw * (double)raw);
    v0D[tid] = (double)raw / sqrt(n2);
  }
  __syncthreads();

  const double PI_D = 3.14159265358979323846;

  // ---- build V row j = tid (f64 in-thread, bitwise same as R11) ----
  {
    double vrow[32];
    if (tid == 0) {
#pragma unroll
      for (int t = 0; t < 16; ++t) {
        double2 w = *(const double2*)(v0D + 2 * t);
        vrow[2 * t] = w.x; vrow[2 * t + 1] = w.y;
      }
    } else {
      uint32_t base = ((uint32_t)(b * NVARS + tid)) * KDIM;
#pragma unroll
      for (int q = 0; q < 32; ++q)
        vrow[q] = (double)bits_to_normal(pbits(b0, b1, base + (uint32_t)q));
      double dot = 0.0;
#pragma unroll
      for (int t = 0; t < 16; ++t) {
        double2 w = *(const double2*)(v0D + 2 * t);
        dot += vrow[2 * t] * w.x + vrow[2 * t + 1] * w.y;
      }
#pragma unroll
      for (int t = 0; t < 16; ++t) {
        double2 w = *(const double2*)(v0D + 2 * t);
        vrow[2 * t]     -= dot * w.x;
        vrow[2 * t + 1] -= dot * w.y;
      }
      double n2 = 0.0;
#pragma unroll
      for (int q = 0; q < 32; ++q) n2 += vrow[q] * vrow[q];
      double rinv = 1.0 / sqrt(n2);
#pragma unroll
      for (int q = 0; q < 32; ++q) vrow[q] *= rinv;
      if (tid <= NIN && is_in[b * NIN + tid - 1] > 0) {
        double zf = (double)zin[b * NIN + tid - 1];
        double cc = cos(PI_D * zf), sn = sin(PI_D * zf);
#pragma unroll
        for (int t = 0; t < 16; ++t) {
          double2 w = *(const double2*)(v0D + 2 * t);
          vrow[2 * t]     = -cc * w.x + sn * vrow[2 * t];
          vrow[2 * t + 1] = -cc * w.y + sn * vrow[2 * t + 1];
        }
      }
    }
#pragma unroll
    for (int q = 0; q < 8; ++q) {
      float4 w;
      w.x = (float)vrow[4 * q];     w.y = (float)vrow[4 * q + 1];
      w.z = (float)vrow[4 * q + 2]; w.w = (float)vrow[4 * q + 3];
      *(float4*)(Vs + tid * 32 + 4 * q) = w;
    }
  }
  __syncthreads();

  // ---- init G: Gj[l*4+m] = G[8jg+l][4kg+m] (f32, ascending i; as R11) ----
  float Gj[32];
#pragma unroll
  for (int q = 0; q < 32; ++q) Gj[q] = 0.f;
  {
    const float* Cb = C32 + (size_t)(8 * jg) * NVARS;
    for (int i = 0; i < NVARS; i += 4) {
      float4 cw[8];
#pragma unroll
      for (int l = 0; l < 8; ++l)
        cw[l] = *(const float4*)(Cb + (size_t)l * NVARS + i);
#pragma unroll
      for (int u = 0; u < 4; ++u) {
        float4 vv = *(const float4*)(Vs + (i + u) * 32 + 4 * kg);
#pragma unroll
        for (int l = 0; l < 8; ++l) {
          float cu = (u == 0) ? cw[l].x : (u == 1) ? cw[l].y
                   : (u == 2) ? cw[l].z : cw[l].w;
          Gj[l * 4 + 0] = fmaf(cu, vv.x, Gj[l * 4 + 0]);
          Gj[l * 4 + 1] = fmaf(cu, vv.y, Gj[l * 4 + 1]);
          Gj[l * 4 + 2] = fmaf(cu, vv.z, Gj[l * 4 + 2]);
          Gj[l * 4 + 3] = fmaf(cu, vv.w, Gj[l * 4 + 3]);
        }
      }
    }
  }
  __syncthreads();

  // ---- solve: producer/consumer span pipeline ----
  int spar = 0;
  for (int it = 0; it < MAXIT; ++it) {
    for (int g = 0; g < 16; ++g) {
      // stage Cd(g); reset next-parity counter
      {
        int r = tid >> 4, c4 = (tid & 15) << 2;
        float4 cc = *(const float4*)(C32 + (size_t)(64 * g + r) * NVARS
                                     + 64 * g + c4);
        *(float4*)(Cd + r * 64 + c4) = cc;
      }
      const uint32_t fl = fmask[2 * g], fh = fmask[2 * g + 1];
      if (wave == g && lane == 0) progV[spar ^ 1] = 0;
      __syncthreads();

      if (wave == g) {
        // -------- producer: serial Gauss-Seidel over own span --------
        int n = 0;
        const int base = 64 * g;
#pragma unroll
        for (int ii = 0; ii < 64; ++ii) {
          bool on = (ii < 32) ? ((myLo >> ii) & 1u) : ((myHi >> (ii - 32)) & 1u);
          if (!on) continue;                 // wave-uniform
          const int m = ii >> 3, l = ii & 7;
          const int row = base + ii;
          float4 c0 = *(const float4*)(Cd + ii * 64 + 8 * jgR);
          float4 c1 = *(const float4*)(Cd + ii * 64 + 8 * jgR + 4);
          float4 vold = *(const float4*)(Vs + row * 32 + 4 * kg);
          float s = Gj[l * 4 + 0] * Gj[l * 4 + 0];
          s = fmaf(Gj[l * 4 + 1], Gj[l * 4 + 1], s);
          s = fmaf(Gj[l * 4 + 2], Gj[l * 4 + 2], s);
          s = fmaf(Gj[l * 4 + 3], Gj[l * 4 + 3], s);
          s += __shfl_xor(s, 1);
          s += __shfl_xor(s, 2);
          s += __shfl_xor(s, 4);
          float gn  = fmaxf(sqrtf(s), 1e-12f);
          float inv = -1.0f / gn;
          float4 vnew, d;
          vnew.x = Gj[l * 4 + 0] * inv; d.x = vnew.x - vold.x;
          vnew.y = Gj[l * 4 + 1] * inv; d.y = vnew.y - vold.y;
          vnew.z = Gj[l * 4 + 2] * inv; d.z = vnew.z - vold.z;
          vnew.w = Gj[l * 4 + 3] * inv; d.w = vnew.w - vold.w;
          if (jgR == m) {
            *(float4*)(Vs + row * 32 + 4 * kg) = vnew;
            *(float4*)(dVs + n * 32 + 4 * kg) = d;
          }
          d.x = __shfl(d.x, 8 * m + kg);
          d.y = __shfl(d.y, 8 * m + kg);
          d.z = __shfl(d.z, 8 * m + kg);
          d.w = __shfl(d.w, 8 * m + kg);
          // publish before own-FMA tail (consumers can start immediately)
          __threadfence_block();
          if (lane == 0) progV[spar] = n + 1;
          Gj[0]  = fmaf(c0.x, d.x, Gj[0]);  Gj[1]  = fmaf(c0.x, d.y, Gj[1]);
          Gj[2]  = fmaf(c0.x, d.z, Gj[2]);  Gj[3]  = fmaf(c0.x, d.w, Gj[3]);
          Gj[4]  = fmaf(c0.y, d.x, Gj[4]);  Gj[5]  = fmaf(c0.y, d.y, Gj[5]);
          Gj[6]  = fmaf(c0.y, d.z, Gj[6]);  Gj[7]  = fmaf(c0.y, d.w, Gj[7]);
          Gj[8]  = fmaf(c0.z, d.x, Gj[8]);  Gj[9]  = fmaf(c0.z, d.y, Gj[9]);
          Gj[10] = fmaf(c0.z, d.z, Gj[10]); Gj[11] = fmaf(c0.z, d.w, Gj[11]);
          Gj[12] = fmaf(c0.w, d.x, Gj[12]); Gj[13] = fmaf(c0.w, d.y, Gj[13]);
          Gj[14] = fmaf(c0.w, d.z, Gj[14]); Gj[15] = fmaf(c0.w, d.w, Gj[15]);
          Gj[16] = fmaf(c1.x, d.x, Gj[16]); Gj[17] = fmaf(c1.x, d.y, Gj[17]);
          Gj[18] = fmaf(c1.x, d.z, Gj[18]); Gj[19] = fmaf(c1.x, d.w, Gj[19]);
          Gj[20] = fmaf(c1.y, d.x, Gj[20]); Gj[21] = fmaf(c1.y, d.y, Gj[21]);
          Gj[22] = fmaf(c1.y, d.z, Gj[22]); Gj[23] = fmaf(c1.y, d.w, Gj[23]);
          Gj[24] = fmaf(c1.z, d.x, Gj[24]); Gj[25] = fmaf(c1.z, d.y, Gj[25]);
          Gj[26] = fmaf(c1.z, d.z, Gj[26]); Gj[27] = fmaf(c1.z, d.w, Gj[27]);
          Gj[28] = fmaf(c1.w, d.x, Gj[28]); Gj[29] = fmaf(c1.w, d.y, Gj[29]);
          Gj[30] = fmaf(c1.w, d.z, Gj[30]); Gj[31] = fmaf(c1.w, d.w, Gj[31]);
          ++n;
        }
      } else {
        // -------- consumer: apply published dvs, C prefetched 1 ahead --------
        uint64_t pb = ((uint64_t)fh << 32) | (uint64_t)fl;
        const int cnt = (int)__builtin_popcountll(pb);
        float4 a0c, a1c, b0c, b1c;
        int rA = pop64(pb);
        if (rA >= 0) {
          const float* p = C32 + (size_t)(64 * g + rA) * NVARS + 8 * jg;
          a0c = *(const float4*)p; a1c = *(const float4*)(p + 4);
        }
        for (int n2 = 0; n2 < cnt; ++n2) {
          int rB = pop64(pb);
          if (rB >= 0) {
            const float* p = C32 + (size_t)(64 * g + rB) * NVARS + 8 * jg;
            b0c = *(const float4*)p; b1c = *(const float4*)(p + 4);
          }
          while (progV[spar] <= n2) __builtin_amdgcn_s_sleep(1);
          float4 d = *(const float4*)(dVs + n2 * 32 + 4 * kg);
          Gj[0]  = fmaf(a0c.x, d.x, Gj[0]);  Gj[1]  = fmaf(a0c.x, d.y, Gj[1]);
          Gj[2]  = fmaf(a0c.x, d.z, Gj[2]);  Gj[3]  = fmaf(a0c.x, d.w, Gj[3]);
          Gj[4]  = fmaf(a0c.y, d.x, Gj[4]);  Gj[5]  = fmaf(a0c.y, d.y, Gj[5]);
          Gj[6]  = fmaf(a0c.y, d.z, Gj[6]);  Gj[7]  = fmaf(a0c.y, d.w, Gj[7]);
          Gj[8]  = fmaf(a0c.z, d.x, Gj[8]);  Gj[9]  = fmaf(a0c.z, d.y, Gj[9]);
          Gj[10] = fmaf(a0c.z, d.z, Gj[10]); Gj[11] = fmaf(a0c.z, d.w, Gj[11]);
          Gj[12] = fmaf(a0c.w, d.x, Gj[12]); Gj[13] = fmaf(a0c.w, d.y, Gj[13]);
          Gj[14] = fmaf(a0c.w, d.z, Gj[14]); Gj[15] = fmaf(a0c.w, d.w, Gj[15]);
          Gj[16] = fmaf(a1c.x, d.x, Gj[16]); Gj[17] = fmaf(a1c.x, d.y, Gj[17]);
          Gj[18] = fmaf(a1c.x, d.z, Gj[18]); Gj[19] = fmaf(a1c.x, d.w, Gj[19]);
          Gj[20] = fmaf(a1c.y, d.x, Gj[20]); Gj[21] = fmaf(a1c.y, d.y, Gj[21]);
          Gj[22] = fmaf(a1c.y, d.z, Gj[22]); Gj[23] = fmaf(a1c.y, d.w, Gj[23]);
          Gj[24] = fmaf(a1c.z, d.x, Gj[24]); Gj[25] = fmaf(a1c.z, d.y, Gj[25]);
          Gj[26] = fmaf(a1c.z, d.z, Gj[26]); Gj[27] = fmaf(a1c.z, d.w, Gj[27]);
          Gj[28] = fmaf(a1c.w, d.x, Gj[28]); Gj[29] = fmaf(a1c.w, d.y, Gj[29]);
          Gj[30] = fmaf(a1c.w, d.z, Gj[30]); Gj[31] = fmaf(a1c.w, d.w, Gj[31]);
          a0c = b0c; a1c = b1c;
        }
      }
      spar ^= 1;
      __syncthreads();   // span end (ring + Vs(span) now consistent)
    }
  }

  // ---- epilogue: thread=j, V from Vs, f64 ----
  if (tid >= 1 && tid <= NIN) {
    bool fr = (fmask[tid >> 5] >> (tid & 31)) & 1u;
    float zo;
    if (fr) {
      double dot = 0.0;
#pragma unroll
      for (int t = 0; t < 16; ++t) {
        double2 w = *(const double2*)(v0D + 2 * t);
        dot += (double)Vs[tid * 32 + 2 * t] * w.x
             + (double)Vs[tid * 32 + 2 * t + 1] * w.y;
      }
      double ca = fmin(fmax(-dot, -1.0 + 1e-7), 1.0 - 1e-7);
      zo = (float)(acos(ca) / PI_D);
    } else {
      zo = zin[b * NIN + tid - 1];
    }
    out[b * NIN + tid - 1] = zo;
  }
}

extern "C" void kernel_launch(void* const* d_in, const int* in_sizes, int n_in,
                              void* d_out, int out_size, void* d_ws, size_t ws_size,
                              hipStream_t stream) {
  const float* C        = (const float*)d_in[0];
  const float* z        = (const float*)d_in[1];
  const int*   is_input = (const int*)d_in[2];
  float*       out      = (float*)d_out;
  (void)d_ws; (void)ws_size;

  (void)hipFuncSetAttribute((const void*)mixnet_kernel,
                            hipFuncAttributeMaxDynamicSharedMemorySize,
                            SMEM_BYTES);

  mixnet_kernel<<<BATCH, 1024, SMEM_BYTES, stream>>>(C, z, is_input, out);
}

// Round 13
// 3612.340 us; speedup vs baseline: 1.3121x; 1.0704x over previous
//
#include <hip/hip_runtime.h>
#include <stdint.h>
#include <math.h>

#define NVARS 1024
#define KDIM 32
#define BATCH 64
#define NIN 768
#define MAXIT 10

// LDS layout (bytes):
//   Vs    @ 0       float [1024][32]   131072   (V state)
//   Cd    @ 131072  float [64][64]      16384   (span diagonal block, producer coeffs)
//   dVs   @ 147456  float [64][32]       8192   (span dv ring, publish-order indexed)
//   fmask @ 155648  uint  [32]            128
//   v0D   @ 155776  double[32]            256
//   prog  @ 156032  int   [2]              64   (publish counters, parity-buffered)
#define SMEM_BYTES 156096

// ---- threefry2x32 block, exactly matching JAX (20 rounds, inject every 4) ----
__device__ __forceinline__ void tf2x32(uint32_t key0, uint32_t key1,
                                       uint32_t& x0, uint32_t& x1) {
  uint32_t ks2 = key0 ^ key1 ^ 0x1BD11BDAu;
  x0 += key0; x1 += key1;
#define TFR(r) { x0 += x1; x1 = (x1 << r) | (x1 >> (32 - r)); x1 ^= x0; }
  TFR(13) TFR(15) TFR(26) TFR(6)
  x0 += key1; x1 += ks2 + 1u;
  TFR(17) TFR(29) TFR(16) TFR(24)
  x0 += ks2;  x1 += key0 + 2u;
  TFR(13) TFR(15) TFR(26) TFR(6)
  x0 += key0; x1 += key1 + 3u;
  TFR(17) TFR(29) TFR(16) TFR(24)
  x0 += key1; x1 += ks2 + 4u;
  TFR(13) TFR(15) TFR(26) TFR(6)
  x0 += ks2;  x1 += key0 + 5u;
#undef TFR
}

// partitionable random_bits (32-bit): counter (0, flat), out = x0 ^ x1
__device__ __forceinline__ uint32_t pbits(uint32_t k0, uint32_t k1, uint32_t flat) {
  uint32_t x0 = 0u, x1 = flat;
  tf2x32(k0, k1, x0, x1);
  return x0 ^ x1;
}

// ---- XLA f32 erf_inv (Giles polynomial) ----
__device__ __forceinline__ float erfinv_xla(float x) {
  float w = -log1pf(-x * x);
  float p;
  if (w < 5.0f) {
    w -= 2.5f;
    p = 2.81022636e-08f;
    p = fmaf(p, w, 3.43273939e-07f);
    p = fmaf(p, w, -3.5233877e-06f);
    p = fmaf(p, w, -4.39150654e-06f);
    p = fmaf(p, w, 0.00021858087f);
    p = fmaf(p, w, -0.00125372503f);
    p = fmaf(p, w, -0.00417768164f);
    p = fmaf(p, w, 0.246640727f);
    p = fmaf(p, w, 1.50140941f);
  } else {
    w = sqrtf(w) - 3.0f;
    p = -0.000200214257f;
    p = fmaf(p, w, 0.000100950558f);
    p = fmaf(p, w, 0.00134934322f);
    p = fmaf(p, w, -0.00367342844f);
    p = fmaf(p, w, 0.00573950773f);
    p = fmaf(p, w, -0.0076224613f);
    p = fmaf(p, w, 0.00943887047f);
    p = fmaf(p, w, 1.00167406f);
    p = fmaf(p, w, 2.83297682f);
  }
  return p * x;
}

__device__ __forceinline__ float bits_to_normal(uint32_t bits) {
  uint32_t fb = (bits >> 9) | 0x3F800000u;
  float f = __uint_as_float(fb) - 1.0f;
  const float lo = -0.99999994f;
  float u = fmaf(f, 2.0f, lo);
  u = fmaxf(lo, u);
  return 1.41421356237f * erfinv_xla(u);
}

__device__ __forceinline__ double red32d(double v) {
  v += __shfl_xor(v, 16);
  v += __shfl_xor(v, 8);
  v += __shfl_xor(v, 4);
  v += __shfl_xor(v, 2);
  v += __shfl_xor(v, 1);
  return v;
}

__device__ __forceinline__ int pop64(uint64_t& b) {
  if (b == 0ull) return -1;
  int i = (int)__builtin_ctzll(b);
  b &= b - 1ull;
  return i;
}

// DPP butterfly add step: s += s[cross-lane CTRL]  (VALU-speed, no LDS pipe)
template <int CTRL>
__device__ __forceinline__ float dppadd(float s) {
  int v = __builtin_amdgcn_update_dpp(0, __float_as_int(s), CTRL, 0xF, 0xF, true);
  return s + __int_as_float(v);
}

__global__ __launch_bounds__(1024, 4) void mixnet_kernel(
    const float* __restrict__ C32, const float* __restrict__ zin,
    const int* __restrict__ is_in, float* __restrict__ out) {
  extern __shared__ char smemraw[];
  float*    Vs    = (float*)smemraw;                 // [1024][32]
  float*    Cd    = (float*)(smemraw + 131072);      // [64][64]
  float*    dVs   = (float*)(smemraw + 147456);      // [64][32]
  uint32_t* fmask = (uint32_t*)(smemraw + 155648);   // [32]
  double*   v0D   = (double*)(smemraw + 155776);     // [32]
  volatile int* progV = (volatile int*)(smemraw + 156032);  // [2]

  const int tid  = threadIdx.x;
  const int b    = blockIdx.x;
  const int jg   = tid >> 3;    // 0..127: owns G rows 8jg..8jg+7
  const int kg   = tid & 7;     // 0..7 : owns k 4kg..4kg+3
  const int lane = tid & 63;
  const int wave = tid >> 6;    // 0..15 = span owner index
  const int jgR  = jg & 7;      // row-group within own span

  // ---- free bits (wave w ballots rows 64w..64w+64) ----
  uint32_t myLo, myHi;
  {
    int row = tid;
    bool fr;
    if (row == 0) fr = false;
    else if (row <= NIN) fr = (is_in[b * NIN + row - 1] == 0);
    else fr = true;
    unsigned long long m = __ballot(fr);
    myLo = (uint32_t)m; myHi = (uint32_t)(m >> 32);
    if (lane == 0) { fmask[2 * wave] = myLo; fmask[2 * wave + 1] = myHi; }
  }
  if (tid == 0) { progV[0] = 0; progV[1] = 0; }

  // k1, k2 = jax.random.split(jax.random.key(42))  [partitionable]
  uint32_t a0 = 0u, a1 = 0u; tf2x32(0u, 42u, a0, a1);
  uint32_t b0 = 0u, b1 = 1u; tf2x32(0u, 42u, b0, b1);

  // ---- v0: threads 0..31 (butterfly, bitwise same as R12) ----
  if (tid < 32) {
    float raw = bits_to_normal(pbits(a0, a1, (uint32_t)(b * KDIM + tid)));
    double n2 = red32d((double)raw * (double)raw);
    v0D[tid] = (double)raw / sqrt(n2);
  }
  __syncthreads();

  const double PI_D = 3.14159265358979323846;

  // ---- build V row j = tid (f64 in-thread, bitwise same as R12) ----
  {
    double vrow[32];
    if (tid == 0) {
#pragma unroll
      for (int t = 0; t < 16; ++t) {
        double2 w = *(const double2*)(v0D + 2 * t);
        vrow[2 * t] = w.x; vrow[2 * t + 1] = w.y;
      }
    } else {
      uint32_t base = ((uint32_t)(b * NVARS + tid)) * KDIM;
#pragma unroll
      for (int q = 0; q < 32; ++q)
        vrow[q] = (double)bits_to_normal(pbits(b0, b1, base + (uint32_t)q));
      double dot = 0.0;
#pragma unroll
      for (int t = 0; t < 16; ++t) {
        double2 w = *(const double2*)(v0D + 2 * t);
        dot += vrow[2 * t] * w.x + vrow[2 * t + 1] * w.y;
      }
#pragma unroll
      for (int t = 0; t < 16; ++t) {
        double2 w = *(const double2*)(v0D + 2 * t);
        vrow[2 * t]     -= dot * w.x;
        vrow[2 * t + 1] -= dot * w.y;
      }
      double n2 = 0.0;
#pragma unroll
      for (int q = 0; q < 32; ++q) n2 += vrow[q] * vrow[q];
      double rinv = 1.0 / sqrt(n2);
#pragma unroll
      for (int q = 0; q < 32; ++q) vrow[q] *= rinv;
      if (tid <= NIN && is_in[b * NIN + tid - 1] > 0) {
        double zf = (double)zin[b * NIN + tid - 1];
        double cc = cos(PI_D * zf), sn = sin(PI_D * zf);
#pragma unroll
        for (int t = 0; t < 16; ++t) {
          double2 w = *(const double2*)(v0D + 2 * t);
          vrow[2 * t]     = -cc * w.x + sn * vrow[2 * t];
          vrow[2 * t + 1] = -cc * w.y + sn * vrow[2 * t + 1];
        }
      }
    }
#pragma unroll
    for (int q = 0; q < 8; ++q) {
      float4 w;
      w.x = (float)vrow[4 * q];     w.y = (float)vrow[4 * q + 1];
      w.z = (float)vrow[4 * q + 2]; w.w = (float)vrow[4 * q + 3];
      *(float4*)(Vs + tid * 32 + 4 * q) = w;
    }
  }
  __syncthreads();

  // ---- init G: Gj[l*4+m] = G[8jg+l][4kg+m] (f32, ascending i; as R12) ----
  float Gj[32];
#pragma unroll
  for (int q = 0; q < 32; ++q) Gj[q] = 0.f;
  {
    const float* Cb = C32 + (size_t)(8 * jg) * NVARS;
    for (int i = 0; i < NVARS; i += 4) {
      float4 cw[8];
#pragma unroll
      for (int l = 0; l < 8; ++l)
        cw[l] = *(const float4*)(Cb + (size_t)l * NVARS + i);
#pragma unroll
      for (int u = 0; u < 4; ++u) {
        float4 vv = *(const float4*)(Vs + (i + u) * 32 + 4 * kg);
#pragma unroll
        for (int l = 0; l < 8; ++l) {
          float cu = (u == 0) ? cw[l].x : (u == 1) ? cw[l].y
                   : (u == 2) ? cw[l].z : cw[l].w;
          Gj[l * 4 + 0] = fmaf(cu, vv.x, Gj[l * 4 + 0]);
          Gj[l * 4 + 1] = fmaf(cu, vv.y, Gj[l * 4 + 1]);
          Gj[l * 4 + 2] = fmaf(cu, vv.z, Gj[l * 4 + 2]);
          Gj[l * 4 + 3] = fmaf(cu, vv.w, Gj[l * 4 + 3]);
        }
      }
    }
  }
  __syncthreads();

  // ---- solve: producer/consumer span pipeline ----
  int spar = 0;
  for (int it = 0; it < MAXIT; ++it) {
    for (int g = 0; g < 16; ++g) {
      // stage Cd(g); reset next-parity counter
      {
        int r = tid >> 4, c4 = (tid & 15) << 2;
        float4 cc = *(const float4*)(C32 + (size_t)(64 * g + r) * NVARS
                                     + 64 * g + c4);
        *(float4*)(Cd + r * 64 + c4) = cc;
      }
      const uint32_t fl = fmask[2 * g], fh = fmask[2 * g + 1];
      if (wave == g && lane == 0) progV[spar ^ 1] = 0;
      __syncthreads();

      if (wave == g) {
        // -------- producer: serial Gauss-Seidel over own span --------
        int n = 0;
        const int base = 64 * g;
#pragma unroll
        for (int ii = 0; ii < 64; ++ii) {
          bool on = (ii < 32) ? ((myLo >> ii) & 1u) : ((myHi >> (ii - 32)) & 1u);
          if (!on) continue;                 // wave-uniform
          const int m = ii >> 3, l = ii & 7;
          const int row = base + ii;
          float4 c0 = *(const float4*)(Cd + ii * 64 + 8 * jgR);
          float4 c1 = *(const float4*)(Cd + ii * 64 + 8 * jgR + 4);
          float4 vold = *(const float4*)(Vs + row * 32 + 4 * kg);
          // norm reduce: same butterfly as shfl_xor(1,2,4) but DPP-speed.
          // After xor1+xor2 the value is quad-uniform, so row_half_mirror
          // (0x141) delivers exactly the xor-4 partner's value (bit-identical).
          float s = Gj[l * 4 + 0] * Gj[l * 4 + 0];
          s = fmaf(Gj[l * 4 + 1], Gj[l * 4 + 1], s);
          s = fmaf(Gj[l * 4 + 2], Gj[l * 4 + 2], s);
          s = fmaf(Gj[l * 4 + 3], Gj[l * 4 + 3], s);
          s = dppadd<0xB1>(s);    // quad_perm [1,0,3,2]  == xor 1
          s = dppadd<0x4E>(s);    // quad_perm [2,3,0,1]  == xor 2
          s = dppadd<0x141>(s);   // row_half_mirror      == xor 4 (quad-uniform)
          float gn  = fmaxf(sqrtf(s), 1e-12f);
          float inv = -1.0f / gn;
          float4 vnew, d;
          vnew.x = Gj[l * 4 + 0] * inv; d.x = vnew.x - vold.x;
          vnew.y = Gj[l * 4 + 1] * inv; d.y = vnew.y - vold.y;
          vnew.z = Gj[l * 4 + 2] * inv; d.z = vnew.z - vold.z;
          vnew.w = Gj[l * 4 + 3] * inv; d.w = vnew.w - vold.w;
          if (jgR == m) {
            *(float4*)(Vs + row * 32 + 4 * kg) = vnew;
            *(float4*)(dVs + n * 32 + 4 * kg) = d;
          }
          // publish after dVs store is visible; own tail reads d back from LDS
          __threadfence_block();
          if (lane == 0) progV[spar] = n + 1;
          float4 dd = *(const float4*)(dVs + n * 32 + 4 * kg);
          Gj[0]  = fmaf(c0.x, dd.x, Gj[0]);  Gj[1]  = fmaf(c0.x, dd.y, Gj[1]);
          Gj[2]  = fmaf(c0.x, dd.z, Gj[2]);  Gj[3]  = fmaf(c0.x, dd.w, Gj[3]);
          Gj[4]  = fmaf(c0.y, dd.x, Gj[4]);  Gj[5]  = fmaf(c0.y, dd.y, Gj[5]);
          Gj[6]  = fmaf(c0.y, dd.z, Gj[6]);  Gj[7]  = fmaf(c0.y, dd.w, Gj[7]);
          Gj[8]  = fmaf(c0.z, dd.x, Gj[8]);  Gj[9]  = fmaf(c0.z, dd.y, Gj[9]);
          Gj[10] = fmaf(c0.z, dd.z, Gj[10]); Gj[11] = fmaf(c0.z, dd.w, Gj[11]);
          Gj[12] = fmaf(c0.w, dd.x, Gj[12]); Gj[13] = fmaf(c0.w, dd.y, Gj[13]);
          Gj[14] = fmaf(c0.w, dd.z, Gj[14]); Gj[15] = fmaf(c0.w, dd.w, Gj[15]);
          Gj[16] = fmaf(c1.x, dd.x, Gj[16]); Gj[17] = fmaf(c1.x, dd.y, Gj[17]);
          Gj[18] = fmaf(c1.x, dd.z, Gj[18]); Gj[19] = fmaf(c1.x, dd.w, Gj[19]);
          Gj[20] = fmaf(c1.y, dd.x, Gj[20]); Gj[21] = fmaf(c1.y, dd.y, Gj[21]);
          Gj[22] = fmaf(c1.y, dd.z, Gj[22]); Gj[23] = fmaf(c1.y, dd.w, Gj[23]);
          Gj[24] = fmaf(c1.z, dd.x, Gj[24]); Gj[25] = fmaf(c1.z, dd.y, Gj[25]);
          Gj[26] = fmaf(c1.z, dd.z, Gj[26]); Gj[27] = fmaf(c1.z, dd.w, Gj[27]);
          Gj[28] = fmaf(c1.w, dd.x, Gj[28]); Gj[29] = fmaf(c1.w, dd.y, Gj[29]);
          Gj[30] = fmaf(c1.w, dd.z, Gj[30]); Gj[31] = fmaf(c1.w, dd.w, Gj[31]);
          ++n;
        }
      } else {
        // -------- consumer: apply published dvs, C prefetched 1 ahead --------
        uint64_t pb = ((uint64_t)fh << 32) | (uint64_t)fl;
        const int cnt = (int)__builtin_popcountll(pb);
        float4 a0c, a1c, b0c, b1c;
        int rA = pop64(pb);
        if (rA >= 0) {
          const float* p = C32 + (size_t)(64 * g + rA) * NVARS + 8 * jg;
          a0c = *(const float4*)p; a1c = *(const float4*)(p + 4);
        }
        for (int n2 = 0; n2 < cnt; ++n2) {
          int rB = pop64(pb);
          if (rB >= 0) {
            const float* p = C32 + (size_t)(64 * g + rB) * NVARS + 8 * jg;
            b0c = *(const float4*)p; b1c = *(const float4*)(p + 4);
          }
          while (progV[spar] <= n2) __builtin_amdgcn_s_sleep(1);
          float4 d = *(const float4*)(dVs + n2 * 32 + 4 * kg);
          Gj[0]  = fmaf(a0c.x, d.x, Gj[0]);  Gj[1]  = fmaf(a0c.x, d.y, Gj[1]);
          Gj[2]  = fmaf(a0c.x, d.z, Gj[2]);  Gj[3]  = fmaf(a0c.x, d.w, Gj[3]);
          Gj[4]  = fmaf(a0c.y, d.x, Gj[4]);  Gj[5]  = fmaf(a0c.y, d.y, Gj[5]);
          Gj[6]  = fmaf(a0c.y, d.z, Gj[6]);  Gj[7]  = fmaf(a0c.y, d.w, Gj[7]);
          Gj[8]  = fmaf(a0c.z, d.x, Gj[8]);  Gj[9]  = fmaf(a0c.z, d.y, Gj[9]);
          Gj[10] = fmaf(a0c.z, d.z, Gj[10]); Gj[11] = fmaf(a0c.z, d.w, Gj[11]);
          Gj[12] = fmaf(a0c.w, d.x, Gj[12]); Gj[13] = fmaf(a0c.w, d.y, Gj[13]);
          Gj[14] = fmaf(a0c.w, d.z, Gj[14]); Gj[15] = fmaf(a0c.w, d.w, Gj[15]);
          Gj[16] = fmaf(a1c.x, d.x, Gj[16]); Gj[17] = fmaf(a1c.x, d.y, Gj[17]);
          Gj[18] = fmaf(a1c.x, d.z, Gj[18]); Gj[19] = fmaf(a1c.x, d.w, Gj[19]);
          Gj[20] = fmaf(a1c.y, d.x, Gj[20]); Gj[21] = fmaf(a1c.y, d.y, Gj[21]);
          Gj[22] = fmaf(a1c.y, d.z, Gj[22]); Gj[23] = fmaf(a1c.y, d.w, Gj[23]);
          Gj[24] = fmaf(a1c.z, d.x, Gj[24]); Gj[25] = fmaf(a1c.z, d.y, Gj[25]);
          Gj[26] = fmaf(a1c.z, d.z, Gj[26]); Gj[27] = fmaf(a1c.z, d.w, Gj[27]);
          Gj[28] = fmaf(a1c.w, d.x, Gj[28]); Gj[29] = fmaf(a1c.w, d.y, Gj[29]);
          Gj[30] = fmaf(a1c.w, d.z, Gj[30]); Gj[31] = fmaf(a1c.w, d.w, Gj[31]);
          a0c = b0c; a1c = b1c;
        }
      }
      spar ^= 1;
      __syncthreads();   // span end (ring + Vs(span) now consistent)
    }
  }

  // ---- epilogue: thread=j, V from Vs, f64 ----
  if (tid >= 1 && tid <= NIN) {
    bool fr = (fmask[tid >> 5] >> (tid & 31)) & 1u;
    float zo;
    if (fr) {
      double dot = 0.0;
#pragma unroll
      for (int t = 0; t < 16; ++t) {
        double2 w = *(const double2*)(v0D + 2 * t);
        dot += (double)Vs[tid * 32 + 2 * t] * w.x
             + (double)Vs[tid * 32 + 2 * t + 1] * w.y;
      }
      double ca = fmin(fmax(-dot, -1.0 + 1e-7), 1.0 - 1e-7);
      zo = (float)(acos(ca) / PI_D);
    } else {
      zo = zin[b * NIN + tid - 1];
    }
    out[b * NIN + tid - 1] = zo;
  }
}

extern "C" void kernel_launch(void* const* d_in, const int* in_sizes, int n_in,
                              void* d_out, int out_size, void* d_ws, size_t ws_size,
                              hipStream_t stream) {
  const float* C        = (const float*)d_in[0];
  const float* z        = (const float*)d_in[1];
  const int*   is_input = (const int*)d_in[2];
  float*       out      = (float*)d_out;
  (void)d_ws; (void)ws_size;

  (void)hipFuncSetAttribute((const void*)mixnet_kernel,
                            hipFuncAttributeMaxDynamicSharedMemorySize,
                            SMEM_BYTES);

  mixnet_kernel<<<BATCH, 1024, SMEM_BYTES, stream>>>(C, z, is_input, out);
}

// Round 14
// 3532.358 us; speedup vs baseline: 1.3418x; 1.0226x over previous
//
#include <hip/hip_runtime.h>
#include <stdint.h>
#include <math.h>

#define NVARS 1024
#define KDIM 32
#define BATCH 64
#define NIN 768
#define MAXIT 10

// LDS layout (bytes):
//   Vs    @ 0       float [1024][32]   131072   (V state)
//   Cd    @ 131072  float [64][64]      16384   (span diagonal block, producer coeffs)
//   dVs   @ 147456  float [64][32]       8192   (span dv ring, publish-order indexed)
//   fmask @ 155648  uint  [32]            128
//   v0D   @ 155776  double[32]            256
//   prog  @ 156032  int   [2]              64   (publish counters, parity-buffered)
#define SMEM_BYTES 156096

// ---- threefry2x32 block, exactly matching JAX (20 rounds, inject every 4) ----
__device__ __forceinline__ void tf2x32(uint32_t key0, uint32_t key1,
                                       uint32_t& x0, uint32_t& x1) {
  uint32_t ks2 = key0 ^ key1 ^ 0x1BD11BDAu;
  x0 += key0; x1 += key1;
#define TFR(r) { x0 += x1; x1 = (x1 << r) | (x1 >> (32 - r)); x1 ^= x0; }
  TFR(13) TFR(15) TFR(26) TFR(6)
  x0 += key1; x1 += ks2 + 1u;
  TFR(17) TFR(29) TFR(16) TFR(24)
  x0 += ks2;  x1 += key0 + 2u;
  TFR(13) TFR(15) TFR(26) TFR(6)
  x0 += key0; x1 += key1 + 3u;
  TFR(17) TFR(29) TFR(16) TFR(24)
  x0 += key1; x1 += ks2 + 4u;
  TFR(13) TFR(15) TFR(26) TFR(6)
  x0 += ks2;  x1 += key0 + 5u;
#undef TFR
}

// partitionable random_bits (32-bit): counter (0, flat), out = x0 ^ x1
__device__ __forceinline__ uint32_t pbits(uint32_t k0, uint32_t k1, uint32_t flat) {
  uint32_t x0 = 0u, x1 = flat;
  tf2x32(k0, k1, x0, x1);
  return x0 ^ x1;
}

// ---- XLA f32 erf_inv (Giles polynomial) ----
__device__ __forceinline__ float erfinv_xla(float x) {
  float w = -log1pf(-x * x);
  float p;
  if (w < 5.0f) {
    w -= 2.5f;
    p = 2.81022636e-08f;
    p = fmaf(p, w, 3.43273939e-07f);
    p = fmaf(p, w, -3.5233877e-06f);
    p = fmaf(p, w, -4.39150654e-06f);
    p = fmaf(p, w, 0.00021858087f);
    p = fmaf(p, w, -0.00125372503f);
    p = fmaf(p, w, -0.00417768164f);
    p = fmaf(p, w, 0.246640727f);
    p = fmaf(p, w, 1.50140941f);
  } else {
    w = sqrtf(w) - 3.0f;
    p = -0.000200214257f;
    p = fmaf(p, w, 0.000100950558f);
    p = fmaf(p, w, 0.00134934322f);
    p = fmaf(p, w, -0.00367342844f);
    p = fmaf(p, w, 0.00573950773f);
    p = fmaf(p, w, -0.0076224613f);
    p = fmaf(p, w, 0.00943887047f);
    p = fmaf(p, w, 1.00167406f);
    p = fmaf(p, w, 2.83297682f);
  }
  return p * x;
}

__device__ __forceinline__ float bits_to_normal(uint32_t bits) {
  uint32_t fb = (bits >> 9) | 0x3F800000u;
  float f = __uint_as_float(fb) - 1.0f;
  const float lo = -0.99999994f;
  float u = fmaf(f, 2.0f, lo);
  u = fmaxf(lo, u);
  return 1.41421356237f * erfinv_xla(u);
}

__device__ __forceinline__ double red32d(double v) {
  v += __shfl_xor(v, 16);
  v += __shfl_xor(v, 8);
  v += __shfl_xor(v, 4);
  v += __shfl_xor(v, 2);
  v += __shfl_xor(v, 1);
  return v;
}

__device__ __forceinline__ int pop64(uint64_t& b) {
  if (b == 0ull) return -1;
  int i = (int)__builtin_ctzll(b);
  b &= b - 1ull;
  return i;
}

// DPP butterfly add step: s += s[cross-lane CTRL]  (VALU-speed, no LDS pipe)
template <int CTRL>
__device__ __forceinline__ float dppadd(float s) {
  int v = __builtin_amdgcn_update_dpp(0, __float_as_int(s), CTRL, 0xF, 0xF, true);
  return s + __int_as_float(v);
}

__global__ __launch_bounds__(1024, 4) void mixnet_kernel(
    const float* __restrict__ C32, const float* __restrict__ zin,
    const int* __restrict__ is_in, float* __restrict__ out) {
  extern __shared__ char smemraw[];
  float*    Vs    = (float*)smemraw;                 // [1024][32]
  float*    Cd    = (float*)(smemraw + 131072);      // [64][64]
  float*    dVs   = (float*)(smemraw + 147456);      // [64][32]
  uint32_t* fmask = (uint32_t*)(smemraw + 155648);   // [32]
  double*   v0D   = (double*)(smemraw + 155776);     // [32]
  volatile int* progV = (volatile int*)(smemraw + 156032);  // [2]

  const int tid  = threadIdx.x;
  const int b    = blockIdx.x;
  const int jg   = tid >> 3;    // 0..127: owns G rows 8*jg .. 8*jg+7
  const int kg   = tid & 7;     // 0..7 : owns k 4*kg .. 4*kg+3
  const int lane = tid & 63;
  const int wave = tid >> 6;    // 0..15 = span owner index
  const int jgR  = jg & 7;      // row-group within own span

  // ---- free bits (wave w ballots rows 64w..64w+64) ----
  uint32_t myLo, myHi;
  {
    int row = tid;
    bool fr;
    if (row == 0) fr = false;
    else if (row <= NIN) fr = (is_in[b * NIN + row - 1] == 0);
    else fr = true;
    unsigned long long m = __ballot(fr);
    myLo = (uint32_t)m; myHi = (uint32_t)(m >> 32);
    if (lane == 0) { fmask[2 * wave] = myLo; fmask[2 * wave + 1] = myHi; }
  }
  if (tid == 0) { progV[0] = 0; progV[1] = 0; }

  // k1, k2 = jax.random.split(jax.random.key(42))  [partitionable]
  uint32_t a0 = 0u, a1 = 0u; tf2x32(0u, 42u, a0, a1);
  uint32_t b0 = 0u, b1 = 1u; tf2x32(0u, 42u, b0, b1);

  // ---- v0: threads 0..31 (butterfly, bitwise same as R13) ----
  if (tid < 32) {
    float raw = bits_to_normal(pbits(a0, a1, (uint32_t)(b * KDIM + tid)));
    double n2 = red32d((double)raw * (double)raw);
    v0D[tid] = (double)raw / sqrt(n2);
  }
  __syncthreads();

  const double PI_D = 3.14159265358979323846;

  // ---- build V row j = tid (f64 in-thread, bitwise same as R13) ----
  {
    double vrow[32];
    if (tid == 0) {
#pragma unroll
      for (int t = 0; t < 16; ++t) {
        double2 w = *(const double2*)(v0D + 2 * t);
        vrow[2 * t] = w.x; vrow[2 * t + 1] = w.y;
      }
    } else {
      uint32_t base = ((uint32_t)(b * NVARS + tid)) * KDIM;
#pragma unroll
      for (int q = 0; q < 32; ++q)
        vrow[q] = (double)bits_to_normal(pbits(b0, b1, base + (uint32_t)q));
      double dot = 0.0;
#pragma unroll
      for (int t = 0; t < 16; ++t) {
        double2 w = *(const double2*)(v0D + 2 * t);
        dot += vrow[2 * t] * w.x + vrow[2 * t + 1] * w.y;
      }
#pragma unroll
      for (int t = 0; t < 16; ++t) {
        double2 w = *(const double2*)(v0D + 2 * t);
        vrow[2 * t]     -= dot * w.x;
        vrow[2 * t + 1] -= dot * w.y;
      }
      double n2 = 0.0;
#pragma unroll
      for (int q = 0; q < 32; ++q) n2 += vrow[q] * vrow[q];
      double rinv = 1.0 / sqrt(n2);
#pragma unroll
      for (int q = 0; q < 32; ++q) vrow[q] *= rinv;
      if (tid <= NIN && is_in[b * NIN + tid - 1] > 0) {
        double zf = (double)zin[b * NIN + tid - 1];
        double cc = cos(PI_D * zf), sn = sin(PI_D * zf);
#pragma unroll
        for (int t = 0; t < 16; ++t) {
          double2 w = *(const double2*)(v0D + 2 * t);
          vrow[2 * t]     = -cc * w.x + sn * vrow[2 * t];
          vrow[2 * t + 1] = -cc * w.y + sn * vrow[2 * t + 1];
        }
      }
    }
#pragma unroll
    for (int q = 0; q < 8; ++q) {
      float4 w;
      w.x = (float)vrow[4 * q];     w.y = (float)vrow[4 * q + 1];
      w.z = (float)vrow[4 * q + 2]; w.w = (float)vrow[4 * q + 3];
      *(float4*)(Vs + tid * 32 + 4 * q) = w;
    }
  }
  __syncthreads();

  // ---- init G: Gj[l*4+m] = G[8jg+l][4kg+m] (f32, ascending i; as R13) ----
  float Gj[32];
#pragma unroll
  for (int q = 0; q < 32; ++q) Gj[q] = 0.f;
  {
    const float* Cb = C32 + (size_t)(8 * jg) * NVARS;
    for (int i = 0; i < NVARS; i += 4) {
      float4 cw[8];
#pragma unroll
      for (int l = 0; l < 8; ++l)
        cw[l] = *(const float4*)(Cb + (size_t)l * NVARS + i);
#pragma unroll
      for (int u = 0; u < 4; ++u) {
        float4 vv = *(const float4*)(Vs + (i + u) * 32 + 4 * kg);
#pragma unroll
        for (int l = 0; l < 8; ++l) {
          float cu = (u == 0) ? cw[l].x : (u == 1) ? cw[l].y
                   : (u == 2) ? cw[l].z : cw[l].w;
          Gj[l * 4 + 0] = fmaf(cu, vv.x, Gj[l * 4 + 0]);
          Gj[l * 4 + 1] = fmaf(cu, vv.y, Gj[l * 4 + 1]);
          Gj[l * 4 + 2] = fmaf(cu, vv.z, Gj[l * 4 + 2]);
          Gj[l * 4 + 3] = fmaf(cu, vv.w, Gj[l * 4 + 3]);
        }
      }
    }
  }
  __syncthreads();

  // ---- solve: producer/consumer span pipeline ----
  int spar = 0;
  for (int it = 0; it < MAXIT; ++it) {
    for (int g = 0; g < 16; ++g) {
      // stage Cd(g); reset next-parity counter
      {
        int r = tid >> 4, c4 = (tid & 15) << 2;
        float4 cc = *(const float4*)(C32 + (size_t)(64 * g + r) * NVARS
                                     + 64 * g + c4);
        *(float4*)(Cd + r * 64 + c4) = cc;
      }
      const uint32_t fl = fmask[2 * g], fh = fmask[2 * g + 1];
      if (wave == g && lane == 0) progV[spar ^ 1] = 0;
      __syncthreads();

      if (wave == g) {
        // -------- producer: serial Gauss-Seidel over own span --------
        // Publish protocol relies on same-wave DS ordering: the dVs store
        // and the progV store are both DS ops from this wave, processed
        // in program order by the LDS pipe; consumers observing the new
        // progV are guaranteed to see the dVs data. Only a COMPILER
        // barrier is needed (no s_waitcnt lgkmcnt(0) drain per row).
        int n = 0;
        const int base = 64 * g;
#pragma unroll
        for (int ii = 0; ii < 64; ++ii) {
          bool on = (ii < 32) ? ((myLo >> ii) & 1u) : ((myHi >> (ii - 32)) & 1u);
          if (!on) continue;                 // wave-uniform
          const int m = ii >> 3, l = ii & 7;
          const int row = base + ii;
          float4 c0 = *(const float4*)(Cd + ii * 64 + 8 * jgR);
          float4 c1 = *(const float4*)(Cd + ii * 64 + 8 * jgR + 4);
          float4 vold = *(const float4*)(Vs + row * 32 + 4 * kg);
          // norm reduce: DPP butterfly (bit-identical to shfl_xor 1,2,4)
          float s = Gj[l * 4 + 0] * Gj[l * 4 + 0];
          s = fmaf(Gj[l * 4 + 1], Gj[l * 4 + 1], s);
          s = fmaf(Gj[l * 4 + 2], Gj[l * 4 + 2], s);
          s = fmaf(Gj[l * 4 + 3], Gj[l * 4 + 3], s);
          s = dppadd<0xB1>(s);    // quad_perm [1,0,3,2]  == xor 1
          s = dppadd<0x4E>(s);    // quad_perm [2,3,0,1]  == xor 2
          s = dppadd<0x141>(s);   // row_half_mirror      == xor 4 (quad-uniform)
          float gn  = fmaxf(sqrtf(s), 1e-12f);
          float inv = -1.0f / gn;
          float4 vnew, d;
          vnew.x = Gj[l * 4 + 0] * inv; d.x = vnew.x - vold.x;
          vnew.y = Gj[l * 4 + 1] * inv; d.y = vnew.y - vold.y;
          vnew.z = Gj[l * 4 + 2] * inv; d.z = vnew.z - vold.z;
          vnew.w = Gj[l * 4 + 3] * inv; d.w = vnew.w - vold.w;
          if (jgR == m) {
            *(float4*)(dVs + n * 32 + 4 * kg) = d;
          }
          asm volatile("" ::: "memory");     // compiler barrier only
          if (lane == 0) progV[spar] = n + 1;
          float4 dd = *(const float4*)(dVs + n * 32 + 4 * kg);
          if (jgR == m) {
            *(float4*)(Vs + row * 32 + 4 * kg) = vnew;  // off critical path
          }
          Gj[0]  = fmaf(c0.x, dd.x, Gj[0]);  Gj[1]  = fmaf(c0.x, dd.y, Gj[1]);
          Gj[2]  = fmaf(c0.x, dd.z, Gj[2]);  Gj[3]  = fmaf(c0.x, dd.w, Gj[3]);
          Gj[4]  = fmaf(c0.y, dd.x, Gj[4]);  Gj[5]  = fmaf(c0.y, dd.y, Gj[5]);
          Gj[6]  = fmaf(c0.y, dd.z, Gj[6]);  Gj[7]  = fmaf(c0.y, dd.w, Gj[7]);
          Gj[8]  = fmaf(c0.z, dd.x, Gj[8]);  Gj[9]  = fmaf(c0.z, dd.y, Gj[9]);
          Gj[10] = fmaf(c0.z, dd.z, Gj[10]); Gj[11] = fmaf(c0.z, dd.w, Gj[11]);
          Gj[12] = fmaf(c0.w, dd.x, Gj[12]); Gj[13] = fmaf(c0.w, dd.y, Gj[13]);
          Gj[14] = fmaf(c0.w, dd.z, Gj[14]); Gj[15] = fmaf(c0.w, dd.w, Gj[15]);
          Gj[16] = fmaf(c1.x, dd.x, Gj[16]); Gj[17] = fmaf(c1.x, dd.y, Gj[17]);
          Gj[18] = fmaf(c1.x, dd.z, Gj[18]); Gj[19] = fmaf(c1.x, dd.w, Gj[19]);
          Gj[20] = fmaf(c1.y, dd.x, Gj[20]); Gj[21] = fmaf(c1.y, dd.y, Gj[21]);
          Gj[22] = fmaf(c1.y, dd.z, Gj[22]); Gj[23] = fmaf(c1.y, dd.w, Gj[23]);
          Gj[24] = fmaf(c1.z, dd.x, Gj[24]); Gj[25] = fmaf(c1.z, dd.y, Gj[25]);
          Gj[26] = fmaf(c1.z, dd.z, Gj[26]); Gj[27] = fmaf(c1.z, dd.w, Gj[27]);
          Gj[28] = fmaf(c1.w, dd.x, Gj[28]); Gj[29] = fmaf(c1.w, dd.y, Gj[29]);
          Gj[30] = fmaf(c1.w, dd.z, Gj[30]); Gj[31] = fmaf(c1.w, dd.w, Gj[31]);
          ++n;
        }
      } else {
        // -------- consumer: apply published dvs, C prefetched 1 ahead --------
        uint64_t pb = ((uint64_t)fh << 32) | (uint64_t)fl;
        const int cnt = (int)__builtin_popcountll(pb);
        float4 a0c, a1c, b0c, b1c;
        int rA = pop64(pb);
        if (rA >= 0) {
          const float* p = C32 + (size_t)(64 * g + rA) * NVARS + 8 * jg;
          a0c = *(const float4*)p; a1c = *(const float4*)(p + 4);
        }
        for (int n2 = 0; n2 < cnt; ++n2) {
          int rB = pop64(pb);
          if (rB >= 0) {
            const float* p = C32 + (size_t)(64 * g + rB) * NVARS + 8 * jg;
            b0c = *(const float4*)p; b1c = *(const float4*)(p + 4);
          }
          while (progV[spar] <= n2) __builtin_amdgcn_s_sleep(1);
          float4 d = *(const float4*)(dVs + n2 * 32 + 4 * kg);
          Gj[0]  = fmaf(a0c.x, d.x, Gj[0]);  Gj[1]  = fmaf(a0c.x, d.y, Gj[1]);
          Gj[2]  = fmaf(a0c.x, d.z, Gj[2]);  Gj[3]  = fmaf(a0c.x, d.w, Gj[3]);
          Gj[4]  = fmaf(a0c.y, d.x, Gj[4]);  Gj[5]  = fmaf(a0c.y, d.y, Gj[5]);
          Gj[6]  = fmaf(a0c.y, d.z, Gj[6]);  Gj[7]  = fmaf(a0c.y, d.w, Gj[7]);
          Gj[8]  = fmaf(a0c.z, d.x, Gj[8]);  Gj[9]  = fmaf(a0c.z, d.y, Gj[9]);
          Gj[10] = fmaf(a0c.z, d.z, Gj[10]); Gj[11] = fmaf(a0c.z, d.w, Gj[11]);
          Gj[12] = fmaf(a0c.w, d.x, Gj[12]); Gj[13] = fmaf(a0c.w, d.y, Gj[13]);
          Gj[14] = fmaf(a0c.w, d.z, Gj[14]); Gj[15] = fmaf(a0c.w, d.w, Gj[15]);
          Gj[16] = fmaf(a1c.x, d.x, Gj[16]); Gj[17] = fmaf(a1c.x, d.y, Gj[17]);
          Gj[18] = fmaf(a1c.x, d.z, Gj[18]); Gj[19] = fmaf(a1c.x, d.w, Gj[19]);
          Gj[20] = fmaf(a1c.y, d.x, Gj[20]); Gj[21] = fmaf(a1c.y, d.y, Gj[21]);
          Gj[22] = fmaf(a1c.y, d.z, Gj[22]); Gj[23] = fmaf(a1c.y, d.w, Gj[23]);
          Gj[24] = fmaf(a1c.z, d.x, Gj[24]); Gj[25] = fmaf(a1c.z, d.y, Gj[25]);
          Gj[26] = fmaf(a1c.z, d.z, Gj[26]); Gj[27] = fmaf(a1c.z, d.w, Gj[27]);
          Gj[28] = fmaf(a1c.w, d.x, Gj[28]); Gj[29] = fmaf(a1c.w, d.y, Gj[29]);
          Gj[30] = fmaf(a1c.w, d.z, Gj[30]); Gj[31] = fmaf(a1c.w, d.w, Gj[31]);
          a0c = b0c; a1c = b1c;
        }
      }
      spar ^= 1;
      __syncthreads();   // span end (ring + Vs(span) now consistent)
    }
  }

  // ---- epilogue: thread=j, V from Vs, f64 ----
  if (tid >= 1 && tid <= NIN) {
    bool fr = (fmask[tid >> 5] >> (tid & 31)) & 1u;
    float zo;
    if (fr) {
      double dot = 0.0;
#pragma unroll
      for (int t = 0; t < 16; ++t) {
        double2 w = *(const double2*)(v0D + 2 * t);
        dot += (double)Vs[tid * 32 + 2 * t] * w.x
             + (double)Vs[tid * 32 + 2 * t + 1] * w.y;
      }
      double ca = fmin(fmax(-dot, -1.0 + 1e-7), 1.0 - 1e-7);
      zo = (float)(acos(ca) / PI_D);
    } else {
      zo = zin[b * NIN + tid - 1];
    }
    out[b * NIN + tid - 1] = zo;
  }
}

extern "C" void kernel_launch(void* const* d_in, const int* in_sizes, int n_in,
                              void* d_out, int out_size, void* d_ws, size_t ws_size,
                              hipStream_t stream) {
  const float* C        = (const float*)d_in[0];
  const float* z        = (const float*)d_in[1];
  const int*   is_input = (const int*)d_in[2];
  float*       out      = (float*)d_out;
  (void)d_ws; (void)ws_size;

  (void)hipFuncSetAttribute((const void*)mixnet_kernel,
                            hipFuncAttributeMaxDynamicSharedMemorySize,
                            SMEM_BYTES);

  mixnet_kernel<<<BATCH, 1024, SMEM_BYTES, stream>>>(C, z, is_input, out);
}

// Round 15
// 3001.289 us; speedup vs baseline: 1.5792x; 1.1769x over previous
//
#include <hip/hip_runtime.h>
#include <stdint.h>
#include <math.h>

#define NVARS 1024
#define KDIM 32
#define BATCH 64
#define NIN 768
#define MAXIT 10

// LDS layout (bytes):
//   Vs    @ 0       float [1024][32]   131072   (V state)
//   Cd    @ 131072  float [64][64]      16384   (span diagonal block, producer coeffs)
//   dVs   @ 147456  float [64][32]       8192   (span dv ring, publish-order indexed)
//   fmask @ 155648  uint  [32]            128
//   v0D   @ 155776  double[32]            256
//   prog  @ 156032  int   [2]              64   (publish counters, parity-buffered)
#define SMEM_BYTES 156096

// ---- threefry2x32 block, exactly matching JAX (20 rounds, inject every 4) ----
__device__ __forceinline__ void tf2x32(uint32_t key0, uint32_t key1,
                                       uint32_t& x0, uint32_t& x1) {
  uint32_t ks2 = key0 ^ key1 ^ 0x1BD11BDAu;
  x0 += key0; x1 += key1;
#define TFR(r) { x0 += x1; x1 = (x1 << r) | (x1 >> (32 - r)); x1 ^= x0; }
  TFR(13) TFR(15) TFR(26) TFR(6)
  x0 += key1; x1 += ks2 + 1u;
  TFR(17) TFR(29) TFR(16) TFR(24)
  x0 += ks2;  x1 += key0 + 2u;
  TFR(13) TFR(15) TFR(26) TFR(6)
  x0 += key0; x1 += key1 + 3u;
  TFR(17) TFR(29) TFR(16) TFR(24)
  x0 += key1; x1 += ks2 + 4u;
  TFR(13) TFR(15) TFR(26) TFR(6)
  x0 += ks2;  x1 += key0 + 5u;
#undef TFR
}

// partitionable random_bits (32-bit): counter (0, flat), out = x0 ^ x1
__device__ __forceinline__ uint32_t pbits(uint32_t k0, uint32_t k1, uint32_t flat) {
  uint32_t x0 = 0u, x1 = flat;
  tf2x32(k0, k1, x0, x1);
  return x0 ^ x1;
}

// ---- XLA f32 erf_inv (Giles polynomial) ----
__device__ __forceinline__ float erfinv_xla(float x) {
  float w = -log1pf(-x * x);
  float p;
  if (w < 5.0f) {
    w -= 2.5f;
    p = 2.81022636e-08f;
    p = fmaf(p, w, 3.43273939e-07f);
    p = fmaf(p, w, -3.5233877e-06f);
    p = fmaf(p, w, -4.39150654e-06f);
    p = fmaf(p, w, 0.00021858087f);
    p = fmaf(p, w, -0.00125372503f);
    p = fmaf(p, w, -0.00417768164f);
    p = fmaf(p, w, 0.246640727f);
    p = fmaf(p, w, 1.50140941f);
  } else {
    w = sqrtf(w) - 3.0f;
    p = -0.000200214257f;
    p = fmaf(p, w, 0.000100950558f);
    p = fmaf(p, w, 0.00134934322f);
    p = fmaf(p, w, -0.00367342844f);
    p = fmaf(p, w, 0.00573950773f);
    p = fmaf(p, w, -0.0076224613f);
    p = fmaf(p, w, 0.00943887047f);
    p = fmaf(p, w, 1.00167406f);
    p = fmaf(p, w, 2.83297682f);
  }
  return p * x;
}

__device__ __forceinline__ float bits_to_normal(uint32_t bits) {
  uint32_t fb = (bits >> 9) | 0x3F800000u;
  float f = __uint_as_float(fb) - 1.0f;
  const float lo = -0.99999994f;
  float u = fmaf(f, 2.0f, lo);
  u = fmaxf(lo, u);
  return 1.41421356237f * erfinv_xla(u);
}

__device__ __forceinline__ double red32d(double v) {
  v += __shfl_xor(v, 16);
  v += __shfl_xor(v, 8);
  v += __shfl_xor(v, 4);
  v += __shfl_xor(v, 2);
  v += __shfl_xor(v, 1);
  return v;
}

__device__ __forceinline__ int pop64(uint64_t& b) {
  if (b == 0ull) return -1;
  int i = (int)__builtin_ctzll(b);
  b &= b - 1ull;
  return i;
}

// DPP butterfly add step: s += s[cross-lane CTRL]  (VALU-speed, no LDS pipe)
template <int CTRL>
__device__ __forceinline__ float dppadd(float s) {
  int v = __builtin_amdgcn_update_dpp(0, __float_as_int(s), CTRL, 0xF, 0xF, true);
  return s + __int_as_float(v);
}

__global__ __launch_bounds__(1024, 4) void mixnet_kernel(
    const float* __restrict__ C32, const float* __restrict__ zin,
    const int* __restrict__ is_in, float* __restrict__ out) {
  extern __shared__ char smemraw[];
  float*    Vs    = (float*)smemraw;                 // [1024][32]
  float*    Cd    = (float*)(smemraw + 131072);      // [64][64]
  float*    dVs   = (float*)(smemraw + 147456);      // [64][32]
  uint32_t* fmask = (uint32_t*)(smemraw + 155648);   // [32]
  double*   v0D   = (double*)(smemraw + 155776);     // [32]
  volatile int* progV = (volatile int*)(smemraw + 156032);  // [2]

  const int tid  = threadIdx.x;
  const int b    = blockIdx.x;
  const int jg   = tid >> 3;    // 0..127: owns G rows 8*jg .. 8*jg+7
  const int kg   = tid & 7;     // 0..7 : owns k 4*kg .. 4*kg+3
  const int lane = tid & 63;
  const int wave = tid >> 6;    // 0..15 = span owner index
  const int jgR  = jg & 7;      // row-group within own span

  // ---- free bits (wave w ballots rows 64w..64w+64) ----
  uint32_t myLo, myHi;
  {
    int row = tid;
    bool fr;
    if (row == 0) fr = false;
    else if (row <= NIN) fr = (is_in[b * NIN + row - 1] == 0);
    else fr = true;
    unsigned long long m = __ballot(fr);
    myLo = (uint32_t)m; myHi = (uint32_t)(m >> 32);
    if (lane == 0) { fmask[2 * wave] = myLo; fmask[2 * wave + 1] = myHi; }
  }
  if (tid == 0) { progV[0] = 0; progV[1] = 0; }

  // k1, k2 = jax.random.split(jax.random.key(42))  [partitionable]
  uint32_t a0 = 0u, a1 = 0u; tf2x32(0u, 42u, a0, a1);
  uint32_t b0 = 0u, b1 = 1u; tf2x32(0u, 42u, b0, b1);

  // ---- v0: threads 0..31 (butterfly, bitwise same as R14) ----
  if (tid < 32) {
    float raw = bits_to_normal(pbits(a0, a1, (uint32_t)(b * KDIM + tid)));
    double n2 = red32d((double)raw * (double)raw);
    v0D[tid] = (double)raw / sqrt(n2);
  }
  __syncthreads();

  const double PI_D = 3.14159265358979323846;

  // ---- build V row j = tid (f64 in-thread, bitwise same as R14) ----
  {
    double vrow[32];
    if (tid == 0) {
#pragma unroll
      for (int t = 0; t < 16; ++t) {
        double2 w = *(const double2*)(v0D + 2 * t);
        vrow[2 * t] = w.x; vrow[2 * t + 1] = w.y;
      }
    } else {
      uint32_t base = ((uint32_t)(b * NVARS + tid)) * KDIM;
#pragma unroll
      for (int q = 0; q < 32; ++q)
        vrow[q] = (double)bits_to_normal(pbits(b0, b1, base + (uint32_t)q));
      double dot = 0.0;
#pragma unroll
      for (int t = 0; t < 16; ++t) {
        double2 w = *(const double2*)(v0D + 2 * t);
        dot += vrow[2 * t] * w.x + vrow[2 * t + 1] * w.y;
      }
#pragma unroll
      for (int t = 0; t < 16; ++t) {
        double2 w = *(const double2*)(v0D + 2 * t);
        vrow[2 * t]     -= dot * w.x;
        vrow[2 * t + 1] -= dot * w.y;
      }
      double n2 = 0.0;
#pragma unroll
      for (int q = 0; q < 32; ++q) n2 += vrow[q] * vrow[q];
      double rinv = 1.0 / sqrt(n2);
#pragma unroll
      for (int q = 0; q < 32; ++q) vrow[q] *= rinv;
      if (tid <= NIN && is_in[b * NIN + tid - 1] > 0) {
        double zf = (double)zin[b * NIN + tid - 1];
        double cc = cos(PI_D * zf), sn = sin(PI_D * zf);
#pragma unroll
        for (int t = 0; t < 16; ++t) {
          double2 w = *(const double2*)(v0D + 2 * t);
          vrow[2 * t]     = -cc * w.x + sn * vrow[2 * t];
          vrow[2 * t + 1] = -cc * w.y + sn * vrow[2 * t + 1];
        }
      }
    }
#pragma unroll
    for (int q = 0; q < 8; ++q) {
      float4 w;
      w.x = (float)vrow[4 * q];     w.y = (float)vrow[4 * q + 1];
      w.z = (float)vrow[4 * q + 2]; w.w = (float)vrow[4 * q + 3];
      *(float4*)(Vs + tid * 32 + 4 * q) = w;
    }
  }
  __syncthreads();

  // ---- init G: Gj[l*4+m] = G[8jg+l][4kg+m] (f32, ascending i; as R14) ----
  float Gj[32];
#pragma unroll
  for (int q = 0; q < 32; ++q) Gj[q] = 0.f;
  {
    const float* Cb = C32 + (size_t)(8 * jg) * NVARS;
    for (int i = 0; i < NVARS; i += 4) {
      float4 cw[8];
#pragma unroll
      for (int l = 0; l < 8; ++l)
        cw[l] = *(const float4*)(Cb + (size_t)l * NVARS + i);
#pragma unroll
      for (int u = 0; u < 4; ++u) {
        float4 vv = *(const float4*)(Vs + (i + u) * 32 + 4 * kg);
#pragma unroll
        for (int l = 0; l < 8; ++l) {
          float cu = (u == 0) ? cw[l].x : (u == 1) ? cw[l].y
                   : (u == 2) ? cw[l].z : cw[l].w;
          Gj[l * 4 + 0] = fmaf(cu, vv.x, Gj[l * 4 + 0]);
          Gj[l * 4 + 1] = fmaf(cu, vv.y, Gj[l * 4 + 1]);
          Gj[l * 4 + 2] = fmaf(cu, vv.z, Gj[l * 4 + 2]);
          Gj[l * 4 + 3] = fmaf(cu, vv.w, Gj[l * 4 + 3]);
        }
      }
    }
  }
  __syncthreads();

  // ---- solve: producer/consumer span pipeline ----
  int spar = 0;
  for (int it = 0; it < MAXIT; ++it) {
    for (int g = 0; g < 16; ++g) {
      // stage Cd(g); reset next-parity counter
      {
        int r = tid >> 4, c4 = (tid & 15) << 2;
        float4 cc = *(const float4*)(C32 + (size_t)(64 * g + r) * NVARS
                                     + 64 * g + c4);
        *(float4*)(Cd + r * 64 + c4) = cc;
      }
      const uint32_t fl = fmask[2 * g], fh = fmask[2 * g + 1];
      if (wave == g && lane == 0) progV[spar ^ 1] = 0;
      __syncthreads();

      if (wave == g) {
        // -------- producer: serial Gauss-Seidel over own span --------
        // prio 3: producer gets near-dedicated issue on its SIMD (3
        // consumer waves co-resident otherwise dilute its serial chain 4x).
        __builtin_amdgcn_s_setprio(3);
        int n = 0;
        const int base = 64 * g;
#pragma unroll
        for (int ii = 0; ii < 64; ++ii) {
          bool on = (ii < 32) ? ((myLo >> ii) & 1u) : ((myHi >> (ii - 32)) & 1u);
          if (!on) continue;                 // wave-uniform
          const int m = ii >> 3, l = ii & 7;
          const int row = base + ii;
          float4 c0 = *(const float4*)(Cd + ii * 64 + 8 * jgR);
          float4 c1 = *(const float4*)(Cd + ii * 64 + 8 * jgR + 4);
          float4 vold = *(const float4*)(Vs + row * 32 + 4 * kg);
          // norm reduce: DPP butterfly (bit-identical to shfl_xor 1,2,4)
          float s = Gj[l * 4 + 0] * Gj[l * 4 + 0];
          s = fmaf(Gj[l * 4 + 1], Gj[l * 4 + 1], s);
          s = fmaf(Gj[l * 4 + 2], Gj[l * 4 + 2], s);
          s = fmaf(Gj[l * 4 + 3], Gj[l * 4 + 3], s);
          s = dppadd<0xB1>(s);    // quad_perm [1,0,3,2]  == xor 1
          s = dppadd<0x4E>(s);    // quad_perm [2,3,0,1]  == xor 2
          s = dppadd<0x141>(s);   // row_half_mirror      == xor 4 (quad-uniform)
          float gn  = fmaxf(sqrtf(s), 1e-12f);
          float inv = -1.0f / gn;
          float4 vnew, d;
          vnew.x = Gj[l * 4 + 0] * inv; d.x = vnew.x - vold.x;
          vnew.y = Gj[l * 4 + 1] * inv; d.y = vnew.y - vold.y;
          vnew.z = Gj[l * 4 + 2] * inv; d.z = vnew.z - vold.z;
          vnew.w = Gj[l * 4 + 3] * inv; d.w = vnew.w - vold.w;
          if (jgR == m) {
            *(float4*)(dVs + n * 32 + 4 * kg) = d;
          }
          asm volatile("" ::: "memory");     // compiler barrier only
          if (lane == 0) progV[spar] = n + 1;
          float4 dd = *(const float4*)(dVs + n * 32 + 4 * kg);
          if (jgR == m) {
            *(float4*)(Vs + row * 32 + 4 * kg) = vnew;  // off critical path
          }
          // tail FMAs, reordered: the quad feeding the NEXT row's norm
          // ((ii+1)&7) first — clears its dependency ~56 issue slots sooner.
          // Per-element FMA order across rows unchanged -> bit-identical.
          float carr[8] = {c0.x, c0.y, c0.z, c0.w, c1.x, c1.y, c1.z, c1.w};
#pragma unroll
          for (int t = 0; t < 8; ++t) {
            const int l2 = (t + ((ii + 1) & 7)) & 7;
            const float c = carr[l2];
            Gj[l2 * 4 + 0] = fmaf(c, dd.x, Gj[l2 * 4 + 0]);
            Gj[l2 * 4 + 1] = fmaf(c, dd.y, Gj[l2 * 4 + 1]);
            Gj[l2 * 4 + 2] = fmaf(c, dd.z, Gj[l2 * 4 + 2]);
            Gj[l2 * 4 + 3] = fmaf(c, dd.w, Gj[l2 * 4 + 3]);
          }
          ++n;
        }
        __builtin_amdgcn_s_setprio(0);
      } else {
        // -------- consumer: apply published dvs, C prefetched 1 ahead --------
        uint64_t pb = ((uint64_t)fh << 32) | (uint64_t)fl;
        const int cnt = (int)__builtin_popcountll(pb);
        float4 a0c, a1c, b0c, b1c;
        int rA = pop64(pb);
        if (rA >= 0) {
          const float* p = C32 + (size_t)(64 * g + rA) * NVARS + 8 * jg;
          a0c = *(const float4*)p; a1c = *(const float4*)(p + 4);
        }
        for (int n2 = 0; n2 < cnt; ++n2) {
          int rB = pop64(pb);
          if (rB >= 0) {
            const float* p = C32 + (size_t)(64 * g + rB) * NVARS + 8 * jg;
            b0c = *(const float4*)p; b1c = *(const float4*)(p + 4);
          }
          while (progV[spar] <= n2) __builtin_amdgcn_s_sleep(1);
          float4 d = *(const float4*)(dVs + n2 * 32 + 4 * kg);
          Gj[0]  = fmaf(a0c.x, d.x, Gj[0]);  Gj[1]  = fmaf(a0c.x, d.y, Gj[1]);
          Gj[2]  = fmaf(a0c.x, d.z, Gj[2]);  Gj[3]  = fmaf(a0c.x, d.w, Gj[3]);
          Gj[4]  = fmaf(a0c.y, d.x, Gj[4]);  Gj[5]  = fmaf(a0c.y, d.y, Gj[5]);
          Gj[6]  = fmaf(a0c.y, d.z, Gj[6]);  Gj[7]  = fmaf(a0c.y, d.w, Gj[7]);
          Gj[8]  = fmaf(a0c.z, d.x, Gj[8]);  Gj[9]  = fmaf(a0c.z, d.y, Gj[9]);
          Gj[10] = fmaf(a0c.z, d.z, Gj[10]); Gj[11] = fmaf(a0c.z, d.w, Gj[11]);
          Gj[12] = fmaf(a0c.w, d.x, Gj[12]); Gj[13] = fmaf(a0c.w, d.y, Gj[13]);
          Gj[14] = fmaf(a0c.w, d.z, Gj[14]); Gj[15] = fmaf(a0c.w, d.w, Gj[15]);
          Gj[16] = fmaf(a1c.x, d.x, Gj[16]); Gj[17] = fmaf(a1c.x, d.y, Gj[17]);
          Gj[18] = fmaf(a1c.x, d.z, Gj[18]); Gj[19] = fmaf(a1c.x, d.w, Gj[19]);
          Gj[20] = fmaf(a1c.y, d.x, Gj[20]); Gj[21] = fmaf(a1c.y, d.y, Gj[21]);
          Gj[22] = fmaf(a1c.y, d.z, Gj[22]); Gj[23] = fmaf(a1c.y, d.w, Gj[23]);
          Gj[24] = fmaf(a1c.z, d.x, Gj[24]); Gj[25] = fmaf(a1c.z, d.y, Gj[25]);
          Gj[26] = fmaf(a1c.z, d.z, Gj[26]); Gj[27] = fmaf(a1c.z, d.w, Gj[27]);
          Gj[28] = fmaf(a1c.w, d.x, Gj[28]); Gj[29] = fmaf(a1c.w, d.y, Gj[29]);
          Gj[30] = fmaf(a1c.w, d.z, Gj[30]); Gj[31] = fmaf(a1c.w, d.w, Gj[31]);
          a0c = b0c; a1c = b1c;
        }
      }
      spar ^= 1;
      __syncthreads();   // span end (ring + Vs(span) now consistent)
    }
  }

  // ---- epilogue: thread=j, V from Vs, f64 ----
  if (tid >= 1 && tid <= NIN) {
    bool fr = (fmask[tid >> 5] >> (tid & 31)) & 1u;
    float zo;
    if (fr) {
      double dot = 0.0;
#pragma unroll
      for (int t = 0; t < 16; ++t) {
        double2 w = *(const double2*)(v0D + 2 * t);
        dot += (double)Vs[tid * 32 + 2 * t] * w.x
             + (double)Vs[tid * 32 + 2 * t + 1] * w.y;
      }
      double ca = fmin(fmax(-dot, -1.0 + 1e-7), 1.0 - 1e-7);
      zo = (float)(acos(ca) / PI_D);
    } else {
      zo = zin[b * NIN + tid - 1];
    }
    out[b * NIN + tid - 1] = zo;
  }
}

extern "C" void kernel_launch(void* const* d_in, const int* in_sizes, int n_in,
                              void* d_out, int out_size, void* d_ws, size_t ws_size,
                              hipStream_t stream) {
  const float* C        = (const float*)d_in[0];
  const float* z        = (const float*)d_in[1];
  const int*   is_input = (const int*)d_in[2];
  float*       out      = (float*)d_out;
  (void)d_ws; (void)ws_size;

  (void)hipFuncSetAttribute((const void*)mixnet_kernel,
                            hipFuncAttributeMaxDynamicSharedMemorySize,
                            SMEM_BYTES);

  mixnet_kernel<<<BATCH, 1024, SMEM_BYTES, stream>>>(C, z, is_input, out);
}

// Round 16
// 2977.239 us; speedup vs baseline: 1.5920x; 1.0081x over previous
//
#include <hip/hip_runtime.h>
#include <stdint.h>
#include <math.h>

#define NVARS 1024
#define KDIM 32
#define BATCH 64
#define NIN 768
#define MAXIT 10

// LDS layout (bytes):
//   Vs    @ 0       float [1024][32]   131072   (V state)
//   Cd    @ 131072  float [64][64]      16384   (span diagonal block, producer coeffs)
//   dVs   @ 147456  float [64][32]       8192   (span dv ring, publish-order indexed)
//   fmask @ 155648  uint  [32]            128
//   v0D   @ 155776  double[32]            256
//   prog  @ 156032  int   [2]              64   (publish counters, parity-buffered)
#define SMEM_BYTES 156096

// ---- threefry2x32 block, exactly matching JAX (20 rounds, inject every 4) ----
__device__ __forceinline__ void tf2x32(uint32_t key0, uint32_t key1,
                                       uint32_t& x0, uint32_t& x1) {
  uint32_t ks2 = key0 ^ key1 ^ 0x1BD11BDAu;
  x0 += key0; x1 += key1;
#define TFR(r) { x0 += x1; x1 = (x1 << r) | (x1 >> (32 - r)); x1 ^= x0; }
  TFR(13) TFR(15) TFR(26) TFR(6)
  x0 += key1; x1 += ks2 + 1u;
  TFR(17) TFR(29) TFR(16) TFR(24)
  x0 += ks2;  x1 += key0 + 2u;
  TFR(13) TFR(15) TFR(26) TFR(6)
  x0 += key0; x1 += key1 + 3u;
  TFR(17) TFR(29) TFR(16) TFR(24)
  x0 += key1; x1 += ks2 + 4u;
  TFR(13) TFR(15) TFR(26) TFR(6)
  x0 += ks2;  x1 += key0 + 5u;
#undef TFR
}

// partitionable random_bits (32-bit): counter (0, flat), out = x0 ^ x1
__device__ __forceinline__ uint32_t pbits(uint32_t k0, uint32_t k1, uint32_t flat) {
  uint32_t x0 = 0u, x1 = flat;
  tf2x32(k0, k1, x0, x1);
  return x0 ^ x1;
}

// ---- XLA f32 erf_inv (Giles polynomial) ----
__device__ __forceinline__ float erfinv_xla(float x) {
  float w = -log1pf(-x * x);
  float p;
  if (w < 5.0f) {
    w -= 2.5f;
    p = 2.81022636e-08f;
    p = fmaf(p, w, 3.43273939e-07f);
    p = fmaf(p, w, -3.5233877e-06f);
    p = fmaf(p, w, -4.39150654e-06f);
    p = fmaf(p, w, 0.00021858087f);
    p = fmaf(p, w, -0.00125372503f);
    p = fmaf(p, w, -0.00417768164f);
    p = fmaf(p, w, 0.246640727f);
    p = fmaf(p, w, 1.50140941f);
  } else {
    w = sqrtf(w) - 3.0f;
    p = -0.000200214257f;
    p = fmaf(p, w, 0.000100950558f);
    p = fmaf(p, w, 0.00134934322f);
    p = fmaf(p, w, -0.00367342844f);
    p = fmaf(p, w, 0.00573950773f);
    p = fmaf(p, w, -0.0076224613f);
    p = fmaf(p, w, 0.00943887047f);
    p = fmaf(p, w, 1.00167406f);
    p = fmaf(p, w, 2.83297682f);
  }
  return p * x;
}

__device__ __forceinline__ float bits_to_normal(uint32_t bits) {
  uint32_t fb = (bits >> 9) | 0x3F800000u;
  float f = __uint_as_float(fb) - 1.0f;
  const float lo = -0.99999994f;
  float u = fmaf(f, 2.0f, lo);
  u = fmaxf(lo, u);
  return 1.41421356237f * erfinv_xla(u);
}

__device__ __forceinline__ double red32d(double v) {
  v += __shfl_xor(v, 16);
  v += __shfl_xor(v, 8);
  v += __shfl_xor(v, 4);
  v += __shfl_xor(v, 2);
  v += __shfl_xor(v, 1);
  return v;
}

__device__ __forceinline__ int pop64(uint64_t& b) {
  if (b == 0ull) return -1;
  int i = (int)__builtin_ctzll(b);
  b &= b - 1ull;
  return i;
}

// DPP butterfly add step: s += s[cross-lane CTRL]  (VALU-speed, no LDS pipe)
template <int CTRL>
__device__ __forceinline__ float dppadd(float s) {
  int v = __builtin_amdgcn_update_dpp(0, __float_as_int(s), CTRL, 0xF, 0xF, true);
  return s + __int_as_float(v);
}

__global__ __launch_bounds__(1024, 4) void mixnet_kernel(
    const float* __restrict__ C32, const float* __restrict__ zin,
    const int* __restrict__ is_in, float* __restrict__ out) {
  extern __shared__ char smemraw[];
  float*    Vs    = (float*)smemraw;                 // [1024][32]
  float*    Cd    = (float*)(smemraw + 131072);      // [64][64]
  float*    dVs   = (float*)(smemraw + 147456);      // [64][32]
  uint32_t* fmask = (uint32_t*)(smemraw + 155648);   // [32]
  double*   v0D   = (double*)(smemraw + 155776);     // [32]
  volatile int* progV = (volatile int*)(smemraw + 156032);  // [2]

  const int tid  = threadIdx.x;
  const int b    = blockIdx.x;
  const int jg   = tid >> 3;    // 0..127: owns G rows 8*jg .. 8*jg+7
  const int kg   = tid & 7;     // 0..7 : owns k 4*kg .. 4*kg+3
  const int lane = tid & 63;
  const int wave = tid >> 6;    // 0..15 = span owner index
  const int jgR  = jg & 7;      // row-group within own span

  // ---- free bits (wave w ballots rows 64w..64w+64) ----
  uint32_t myLo, myHi;
  {
    int row = tid;
    bool fr;
    if (row == 0) fr = false;
    else if (row <= NIN) fr = (is_in[b * NIN + row - 1] == 0);
    else fr = true;
    unsigned long long m = __ballot(fr);
    myLo = (uint32_t)m; myHi = (uint32_t)(m >> 32);
    if (lane == 0) { fmask[2 * wave] = myLo; fmask[2 * wave + 1] = myHi; }
  }
  if (tid == 0) { progV[0] = 0; progV[1] = 0; }

  // k1, k2 = jax.random.split(jax.random.key(42))  [partitionable]
  uint32_t a0 = 0u, a1 = 0u; tf2x32(0u, 42u, a0, a1);
  uint32_t b0 = 0u, b1 = 1u; tf2x32(0u, 42u, b0, b1);

  // ---- v0: threads 0..31 (butterfly, bitwise same as R15) ----
  if (tid < 32) {
    float raw = bits_to_normal(pbits(a0, a1, (uint32_t)(b * KDIM + tid)));
    double n2 = red32d((double)raw * (double)raw);
    v0D[tid] = (double)raw / sqrt(n2);
  }
  __syncthreads();

  const double PI_D = 3.14159265358979323846;

  // ---- build V row j = tid (f64 in-thread, bitwise same as R15) ----
  {
    double vrow[32];
    if (tid == 0) {
#pragma unroll
      for (int t = 0; t < 16; ++t) {
        double2 w = *(const double2*)(v0D + 2 * t);
        vrow[2 * t] = w.x; vrow[2 * t + 1] = w.y;
      }
    } else {
      uint32_t base = ((uint32_t)(b * NVARS + tid)) * KDIM;
#pragma unroll
      for (int q = 0; q < 32; ++q)
        vrow[q] = (double)bits_to_normal(pbits(b0, b1, base + (uint32_t)q));
      double dot = 0.0;
#pragma unroll
      for (int t = 0; t < 16; ++t) {
        double2 w = *(const double2*)(v0D + 2 * t);
        dot += vrow[2 * t] * w.x + vrow[2 * t + 1] * w.y;
      }
#pragma unroll
      for (int t = 0; t < 16; ++t) {
        double2 w = *(const double2*)(v0D + 2 * t);
        vrow[2 * t]     -= dot * w.x;
        vrow[2 * t + 1] -= dot * w.y;
      }
      double n2 = 0.0;
#pragma unroll
      for (int q = 0; q < 32; ++q) n2 += vrow[q] * vrow[q];
      double rinv = 1.0 / sqrt(n2);
#pragma unroll
      for (int q = 0; q < 32; ++q) vrow[q] *= rinv;
      if (tid <= NIN && is_in[b * NIN + tid - 1] > 0) {
        double zf = (double)zin[b * NIN + tid - 1];
        double cc = cos(PI_D * zf), sn = sin(PI_D * zf);
#pragma unroll
        for (int t = 0; t < 16; ++t) {
          double2 w = *(const double2*)(v0D + 2 * t);
          vrow[2 * t]     = -cc * w.x + sn * vrow[2 * t];
          vrow[2 * t + 1] = -cc * w.y + sn * vrow[2 * t + 1];
        }
      }
    }
#pragma unroll
    for (int q = 0; q < 8; ++q) {
      float4 w;
      w.x = (float)vrow[4 * q];     w.y = (float)vrow[4 * q + 1];
      w.z = (float)vrow[4 * q + 2]; w.w = (float)vrow[4 * q + 3];
      *(float4*)(Vs + tid * 32 + 4 * q) = w;
    }
  }
  __syncthreads();

  // ---- init G: Gj[l*4+m] = G[8jg+l][4kg+m] (f32, ascending i; as R15) ----
  float Gj[32];
#pragma unroll
  for (int q = 0; q < 32; ++q) Gj[q] = 0.f;
  {
    const float* Cb = C32 + (size_t)(8 * jg) * NVARS;
    for (int i = 0; i < NVARS; i += 4) {
      float4 cw[8];
#pragma unroll
      for (int l = 0; l < 8; ++l)
        cw[l] = *(const float4*)(Cb + (size_t)l * NVARS + i);
#pragma unroll
      for (int u = 0; u < 4; ++u) {
        float4 vv = *(const float4*)(Vs + (i + u) * 32 + 4 * kg);
#pragma unroll
        for (int l = 0; l < 8; ++l) {
          float cu = (u == 0) ? cw[l].x : (u == 1) ? cw[l].y
                   : (u == 2) ? cw[l].z : cw[l].w;
          Gj[l * 4 + 0] = fmaf(cu, vv.x, Gj[l * 4 + 0]);
          Gj[l * 4 + 1] = fmaf(cu, vv.y, Gj[l * 4 + 1]);
          Gj[l * 4 + 2] = fmaf(cu, vv.z, Gj[l * 4 + 2]);
          Gj[l * 4 + 3] = fmaf(cu, vv.w, Gj[l * 4 + 3]);
        }
      }
    }
  }
  __syncthreads();

  // ---- solve: producer/consumer span pipeline ----
  int spar = 0;
  for (int it = 0; it < MAXIT; ++it) {
    for (int g = 0; g < 16; ++g) {
      // stage Cd(g); reset next-parity counter
      {
        int r = tid >> 4, c4 = (tid & 15) << 2;
        float4 cc = *(const float4*)(C32 + (size_t)(64 * g + r) * NVARS
                                     + 64 * g + c4);
        *(float4*)(Cd + r * 64 + c4) = cc;
      }
      const uint32_t fl = fmask[2 * g], fh = fmask[2 * g + 1];
      if (wave == g && lane == 0) progV[spar ^ 1] = 0;
      __syncthreads();

      if (wave == g) {
        // -------- producer: serial Gauss-Seidel over own span --------
        __builtin_amdgcn_s_setprio(3);
        int n = 0;
        const int base = 64 * g;
#pragma unroll
        for (int ii = 0; ii < 64; ++ii) {
          bool on = (ii < 32) ? ((myLo >> ii) & 1u) : ((myHi >> (ii - 32)) & 1u);
          if (!on) continue;                 // wave-uniform
          const int m = ii >> 3, l = ii & 7;
          const int row = base + ii;
          float4 c0 = *(const float4*)(Cd + ii * 64 + 8 * jgR);
          float4 c1 = *(const float4*)(Cd + ii * 64 + 8 * jgR + 4);
          float4 vold = *(const float4*)(Vs + row * 32 + 4 * kg);
          // norm reduce: DPP butterfly (bit-identical to shfl_xor 1,2,4)
          float s = Gj[l * 4 + 0] * Gj[l * 4 + 0];
          s = fmaf(Gj[l * 4 + 1], Gj[l * 4 + 1], s);
          s = fmaf(Gj[l * 4 + 2], Gj[l * 4 + 2], s);
          s = fmaf(Gj[l * 4 + 3], Gj[l * 4 + 3], s);
          s = dppadd<0xB1>(s);    // quad_perm [1,0,3,2]  == xor 1
          s = dppadd<0x4E>(s);    // quad_perm [2,3,0,1]  == xor 2
          s = dppadd<0x141>(s);   // row_half_mirror      == xor 4 (quad-uniform)
          float gn  = fmaxf(sqrtf(s), 1e-12f);
          float inv = -1.0f / gn;
          float4 vnew, d;
          vnew.x = Gj[l * 4 + 0] * inv; d.x = vnew.x - vold.x;
          vnew.y = Gj[l * 4 + 1] * inv; d.y = vnew.y - vold.y;
          vnew.z = Gj[l * 4 + 2] * inv; d.z = vnew.z - vold.z;
          vnew.w = Gj[l * 4 + 3] * inv; d.w = vnew.w - vold.w;
          if (jgR == m) {
            *(float4*)(dVs + n * 32 + 4 * kg) = d;
          }
          asm volatile("" ::: "memory");     // compiler barrier only
          if (lane == 0) progV[spar] = n + 1;
          float4 dd = *(const float4*)(dVs + n * 32 + 4 * kg);
          if (jgR == m) {
            *(float4*)(Vs + row * 32 + 4 * kg) = vnew;  // off critical path
          }
          // tail FMAs: next row's norm quad first (bit-identical order per elem)
          float carr[8] = {c0.x, c0.y, c0.z, c0.w, c1.x, c1.y, c1.z, c1.w};
#pragma unroll
          for (int t = 0; t < 8; ++t) {
            const int l2 = (t + ((ii + 1) & 7)) & 7;
            const float c = carr[l2];
            Gj[l2 * 4 + 0] = fmaf(c, dd.x, Gj[l2 * 4 + 0]);
            Gj[l2 * 4 + 1] = fmaf(c, dd.y, Gj[l2 * 4 + 1]);
            Gj[l2 * 4 + 2] = fmaf(c, dd.z, Gj[l2 * 4 + 2]);
            Gj[l2 * 4 + 3] = fmaf(c, dd.w, Gj[l2 * 4 + 3]);
          }
          ++n;
        }
        __builtin_amdgcn_s_setprio(0);
      } else {
        // ---- consumer: batched wait (4 rows/sync), C prefetched 4-deep ----
        uint64_t pb = ((uint64_t)fh << 32) | (uint64_t)fl;
        const int cnt = (int)__builtin_popcountll(pb);
        float4 cp0[4], cp1[4];
#pragma unroll
        for (int s2 = 0; s2 < 4; ++s2) {
          int r = pop64(pb);
          if (r >= 0) {
            const float* p = C32 + (size_t)(64 * g + r) * NVARS + 8 * jg;
            cp0[s2] = *(const float4*)p; cp1[s2] = *(const float4*)(p + 4);
          }
        }
        int n2 = 0;
        while (n2 < cnt) {
          const int hi = (n2 + 4 < cnt) ? n2 + 4 : cnt;
          while (progV[spar] < hi) __builtin_amdgcn_s_sleep(1);
#pragma unroll
          for (int s2 = 0; s2 < 4; ++s2) {
            if (n2 + s2 < hi) {
              float4 d = *(const float4*)(dVs + (n2 + s2) * 32 + 4 * kg);
              const float4 A0 = cp0[s2], A1 = cp1[s2];
              Gj[0]  = fmaf(A0.x, d.x, Gj[0]);  Gj[1]  = fmaf(A0.x, d.y, Gj[1]);
              Gj[2]  = fmaf(A0.x, d.z, Gj[2]);  Gj[3]  = fmaf(A0.x, d.w, Gj[3]);
              Gj[4]  = fmaf(A0.y, d.x, Gj[4]);  Gj[5]  = fmaf(A0.y, d.y, Gj[5]);
              Gj[6]  = fmaf(A0.y, d.z, Gj[6]);  Gj[7]  = fmaf(A0.y, d.w, Gj[7]);
              Gj[8]  = fmaf(A0.z, d.x, Gj[8]);  Gj[9]  = fmaf(A0.z, d.y, Gj[9]);
              Gj[10] = fmaf(A0.z, d.z, Gj[10]); Gj[11] = fmaf(A0.z, d.w, Gj[11]);
              Gj[12] = fmaf(A0.w, d.x, Gj[12]); Gj[13] = fmaf(A0.w, d.y, Gj[13]);
              Gj[14] = fmaf(A0.w, d.z, Gj[14]); Gj[15] = fmaf(A0.w, d.w, Gj[15]);
              Gj[16] = fmaf(A1.x, d.x, Gj[16]); Gj[17] = fmaf(A1.x, d.y, Gj[17]);
              Gj[18] = fmaf(A1.x, d.z, Gj[18]); Gj[19] = fmaf(A1.x, d.w, Gj[19]);
              Gj[20] = fmaf(A1.y, d.x, Gj[20]); Gj[21] = fmaf(A1.y, d.y, Gj[21]);
              Gj[22] = fmaf(A1.y, d.z, Gj[22]); Gj[23] = fmaf(A1.y, d.w, Gj[23]);
              Gj[24] = fmaf(A1.z, d.x, Gj[24]); Gj[25] = fmaf(A1.z, d.y, Gj[25]);
              Gj[26] = fmaf(A1.z, d.z, Gj[26]); Gj[27] = fmaf(A1.z, d.w, Gj[27]);
              Gj[28] = fmaf(A1.w, d.x, Gj[28]); Gj[29] = fmaf(A1.w, d.y, Gj[29]);
              Gj[30] = fmaf(A1.w, d.z, Gj[30]); Gj[31] = fmaf(A1.w, d.w, Gj[31]);
            }
          }
#pragma unroll
          for (int s2 = 0; s2 < 4; ++s2) {
            int r = pop64(pb);
            if (r >= 0) {
              const float* p = C32 + (size_t)(64 * g + r) * NVARS + 8 * jg;
              cp0[s2] = *(const float4*)p; cp1[s2] = *(const float4*)(p + 4);
            }
          }
          n2 = hi;
        }
      }
      spar ^= 1;
      __syncthreads();   // span end (ring + Vs(span) now consistent)
    }
  }

  // ---- epilogue: thread=j, V from Vs, f64 ----
  if (tid >= 1 && tid <= NIN) {
    bool fr = (fmask[tid >> 5] >> (tid & 31)) & 1u;
    float zo;
    if (fr) {
      double dot = 0.0;
#pragma unroll
      for (int t = 0; t < 16; ++t) {
        double2 w = *(const double2*)(v0D + 2 * t);
        dot += (double)Vs[tid * 32 + 2 * t] * w.x
             + (double)Vs[tid * 32 + 2 * t + 1] * w.y;
      }
      double ca = fmin(fmax(-dot, -1.0 + 1e-7), 1.0 - 1e-7);
      zo = (float)(acos(ca) / PI_D);
    } else {
      zo = zin[b * NIN + tid - 1];
    }
    out[b * NIN + tid - 1] = zo;
  }
}

extern "C" void kernel_launch(void* const* d_in, const int* in_sizes, int n_in,
                              void* d_out, int out_size, void* d_ws, size_t ws_size,
                              hipStream_t stream) {
  const float* C        = (const float*)d_in[0];
  const float* z        = (const float*)d_in[1];
  const int*   is_input = (const int*)d_in[2];
  float*       out      = (float*)d_out;
  (void)d_ws; (void)ws_size;

  (void)hipFuncSetAttribute((const void*)mixnet_kernel,
                            hipFuncAttributeMaxDynamicSharedMemorySize,
                            SMEM_BYTES);

  mixnet_kernel<<<BATCH, 1024, SMEM_BYTES, stream>>>(C, z, is_input, out);
}